// Round 9
// baseline (4135.630 us; speedup 1.0000x reference)
//
#include <hip/hip_runtime.h>
#include <cstddef>
#include <cstdint>

using u16 = unsigned short;
typedef float    f32x4 __attribute__((ext_vector_type(4)));
typedef _Float16 f16x8 __attribute__((ext_vector_type(8)));
typedef u16      us8   __attribute__((ext_vector_type(8)));

constexpr int B  = 128;
constexpr int T  = 20;
constexpr int V  = 20000;
constexpr int DW = 512;
constexpr int H  = 1024;
constexpr int G4 = 4096;
constexpr int NI = 36;
constexpr int NP = 100;
constexpr int SOS = 1;

__device__ __forceinline__ float sigf(float x) { return 1.0f / (1.0f + expf(-x)); }
__device__ __forceinline__ u16 f16bits(_Float16 h) { u16 u; __builtin_memcpy(&u, &h, 2); return u; }
__device__ __forceinline__ float h2f(u16 u) { _Float16 h; __builtin_memcpy(&h, &u, 2); return (float)h; }

// f16x3 split: x ~= hi + lo as triples; one K-expanded f16 GEMM computes
// hi*hi + lo*hi + hi*lo (error ~2^-22). A: [hi, lo*64, hi/64]; W: [hi, hi/64, lo*64]
template<bool WSIDE>
__device__ __forceinline__ void split1(float x, u16& b0, u16& b1, u16& b2) {
    _Float16 h  = (_Float16)x;
    float    hf = (float)h;
    _Float16 lo = (_Float16)((x - hf) * 64.0f);
    _Float16 hs = (_Float16)(hf * (1.0f / 64.0f));
    b0 = f16bits(h);
    if constexpr (WSIDE) { b1 = f16bits(hs); b2 = f16bits(lo); }
    else                 { b1 = f16bits(lo); b2 = f16bits(hs); }
}

// ---------------------------------------------------------------------------
// Generic MFMA GEMM (precompute + proj): C[M,N] = A3[M,K3] x B3t[N,K3]^T.
// BK=64, 4 waves 2x2, software-pipelined. NSW>0: super-tile remap for L3 reuse.
// OUTF16: write C as f16.
// ---------------------------------------------------------------------------
template<int BM, int BN, bool HAS_ADD, bool HAS_BIAS, int NSW = 0, bool OUTF16 = false>
__global__ __launch_bounds__(256)
void gemm3(const u16* __restrict__ A, const u16* __restrict__ Bt,
           const float* __restrict__ Add, const float* __restrict__ bias,
           void* __restrict__ Cv, int N, int K3)
{
    __shared__ __align__(16) u16 As[BM * 64];
    __shared__ __align__(16) u16 Bs[BN * 64];
    constexpr int FR = BM / 32, FC = BN / 32, PA = BM / 32, PB = BN / 32;
    const int tid  = threadIdx.x;
    int bx = blockIdx.x, by = blockIdx.y;
    if constexpr (NSW > 0) {
        const int nt = (int)gridDim.x, mt = (int)gridDim.y;
        const int lin = by * nt + bx;
        const int sc0 = (lin / (NSW * mt)) * NSW;
        const int w   = (NSW < nt - sc0) ? NSW : (nt - sc0);
        const int r   = lin - sc0 * mt;
        bx = sc0 + r % w;
        by = r / w;
    }
    const int bm   = by * BM, bn = bx * BN;
    const int lane = tid & 63, wid = tid >> 6;
    const int wm   = (wid >> 1) * (BM / 2), wn = (wid & 1) * (BN / 2);
    const int srow = tid >> 3;
    const int scol = (tid & 7) * 8;

    f32x4 acc[FR][FC] = {};
    us8 ra[PA], rb[PB];

    auto ldg = [&](int k0) {
#pragma unroll
        for (int p = 0; p < PA; ++p)
            ra[p] = *(const us8*)(A + (size_t)(bm + p * 32 + srow) * K3 + k0 + scol);
#pragma unroll
        for (int p = 0; p < PB; ++p) {
            int n = bn + p * 32 + srow; if (n > N - 1) n = N - 1;
            rb[p] = *(const us8*)(Bt + (size_t)n * K3 + k0 + scol);
        }
    };
    ldg(0);

    for (int k0 = 0; k0 < K3; k0 += 64) {
        __syncthreads();
#pragma unroll
        for (int p = 0; p < PA; ++p) {
            const int row = p * 32 + srow;
            *(us8*)((char*)As + row * 128 + ((scol * 2) ^ ((row & 7) << 4))) = ra[p];
        }
#pragma unroll
        for (int p = 0; p < PB; ++p) {
            const int row = p * 32 + srow;
            *(us8*)((char*)Bs + row * 128 + ((scol * 2) ^ ((row & 7) << 4))) = rb[p];
        }
        __syncthreads();
        if (k0 + 64 < K3) ldg(k0 + 64);
#pragma unroll
        for (int ks = 0; ks < 2; ++ks) {
            f16x8 af[FR], bf[FC];
#pragma unroll
            for (int m = 0; m < FR; ++m) {
                const int row = wm + m * 16 + (lane & 15);
                const int cb  = (ks * 64 + ((lane >> 4) << 4)) ^ ((row & 7) << 4);
                af[m] = *(const f16x8*)((const char*)As + row * 128 + cb);
            }
#pragma unroll
            for (int n = 0; n < FC; ++n) {
                const int row = wn + n * 16 + (lane & 15);
                const int cb  = (ks * 64 + ((lane >> 4) << 4)) ^ ((row & 7) << 4);
                bf[n] = *(const f16x8*)((const char*)Bs + row * 128 + cb);
            }
#pragma unroll
            for (int m = 0; m < FR; ++m)
#pragma unroll
                for (int n = 0; n < FC; ++n)
                    acc[m][n] = __builtin_amdgcn_mfma_f32_16x16x32_f16(af[m], bf[n], acc[m][n], 0, 0, 0);
        }
    }
#pragma unroll
    for (int m = 0; m < FR; ++m) {
        const int r0 = bm + wm + m * 16 + ((lane >> 4) << 2);
#pragma unroll
        for (int n = 0; n < FC; ++n) {
            const int c = bn + wn + n * 16 + (lane & 15);
            if (c < N) {
#pragma unroll
                for (int j = 0; j < 4; ++j) {
                    float v = acc[m][n][j];
                    if constexpr (HAS_ADD)  v += Add[(size_t)(r0 + j) * N + c];
                    if constexpr (HAS_BIAS) v += bias[c];
                    if constexpr (OUTF16)
                        ((u16*)Cv)[(size_t)(r0 + j) * N + c] = f16bits((_Float16)v);
                    else
                        ((float*)Cv)[(size_t)(r0 + j) * N + c] = v;
                }
            }
        }
    }
}

// ---------------------------------------------------------------------------
// In-loop GEMM core (BM=64, BN/BK params), 256 threads, 4 waves each 16 rows x
// BN cols. EPI=0: plain f32 C. EPI=1: vis-LSTM epilogue. EPI=2: lang-LSTM.
// ---------------------------------------------------------------------------
template<int EPI, int BN, int BK>
__device__ __forceinline__ void gemm_core(
    u16* As, u16* Bs,
    const u16* A, const u16* Bt,
    const float* Add, const float* bias,
    float* CS, u16* o1, u16* o2,
    int N, int K3, int t, int bx, int by)
{
    constexpr int NA8  = BK / 32;
    constexpr int TPRB = 256 / BN;
    constexpr int NB8  = (BK / TPRB) / 8;
    constexpr int NFC  = BN / 16;
    const int tid  = threadIdx.x;
    const int bn   = bx * BN, bm = by * 64;
    const int lane = tid & 63, wv = tid >> 6;
    const int rowA = tid >> 2;
    const int scA  = (tid & 3) * (BK / 4);
    const int rowB = tid / TPRB;
    const int scB  = (tid % TPRB) * (BK / TPRB);
    const int swzA = (rowA & 7) << 4;
    const int swzB = (rowB & 7) << 4;
    const u16* Ap = A  + (size_t)(bm + rowA) * K3 + scA;
    const u16* Bp = Bt + (size_t)(bn + rowB) * K3 + scB;
    char* Awp = (char*)As + rowA * (BK * 2);
    char* Bwp = (char*)Bs + rowB * (BK * 2);
    const int arow = wv * 16 + (lane & 15);
    const char* Arp = (const char*)As + arow * (BK * 2);
    const int aswz = (arow & 7) << 4;
    const int jl   = lane & 15;

    f32x4 acc[NFC] = {};
    us8 ra[NA8], rb[NB8];
#pragma unroll
    for (int i = 0; i < NA8; ++i) ra[i] = *(const us8*)(Ap + 8 * i);
#pragma unroll
    for (int i = 0; i < NB8; ++i) rb[i] = *(const us8*)(Bp + 8 * i);

    for (int k0 = 0; k0 < K3; k0 += BK) {
        __syncthreads();
#pragma unroll
        for (int i = 0; i < NA8; ++i)
            *(us8*)(Awp + ((scA * 2 + 16 * i) ^ swzA)) = ra[i];
#pragma unroll
        for (int i = 0; i < NB8; ++i)
            *(us8*)(Bwp + ((scB * 2 + 16 * i) ^ swzB)) = rb[i];
        __syncthreads();
        if (k0 + BK < K3) {
#pragma unroll
            for (int i = 0; i < NA8; ++i) ra[i] = *(const us8*)(Ap + k0 + BK + 8 * i);
#pragma unroll
            for (int i = 0; i < NB8; ++i) rb[i] = *(const us8*)(Bp + k0 + BK + 8 * i);
        }
#pragma unroll
        for (int ks = 0; ks < BK / 32; ++ks) {
            const int cb = ks * 64 + ((lane >> 4) << 4);
            const f16x8 af = *(const f16x8*)(Arp + (cb ^ aswz));
#pragma unroll
            for (int g = 0; g < NFC; ++g) {
                const int brow = g * 16 + jl;
                const f16x8 bf = *(const f16x8*)((const char*)Bs + brow * (BK * 2) + (cb ^ ((brow & 7) << 4)));
                acc[g] = __builtin_amdgcn_mfma_f32_16x16x32_f16(af, bf, acc[g], 0, 0, 0);
            }
        }
    }
    const int rb0 = bm + wv * 16 + ((lane >> 4) << 2);
    if constexpr (EPI == 0) {
#pragma unroll
        for (int g = 0; g < NFC; ++g) {
            const int c = bn + g * 16 + jl;
#pragma unroll
            for (int jj = 0; jj < 4; ++jj)
                CS[(size_t)(rb0 + jj) * N + c] = acc[g][jj];
        }
    } else {
        const int j = bx * 16 + jl;
#pragma unroll
        for (int jj = 0; jj < 4; ++jj) {
            const int b = rb0 + jj;
            float gi = acc[0][jj], gf = acc[1][jj], gg = acc[2][jj], go = acc[3][jj];
            if constexpr (EPI == 1) {
                const float* ap = Add + (size_t)b * 4096 + bn + jl;
                gi += ap[0]; gf += ap[16]; gg += ap[32]; go += ap[48];
            } else {
                const float* bp = bias + bn + jl;
                gi += bp[0]; gf += bp[16]; gg += bp[32]; go += bp[48];
            }
            const float c = sigf(gf) * CS[b * 1024 + j] + sigf(gi) * tanhf(gg);
            const float h = sigf(go) * tanhf(c);
            CS[b * 1024 + j] = c;
            u16 b0, b1, b2; split1<false>(h, b0, b1, b2);
            if constexpr (EPI == 1) {
                u16* a = o1 + (size_t)b * 3072 + j;
                a[0] = b0; a[1024] = b1; a[2048] = b2;
                u16* x = o2 + (size_t)b * 7680 + 512 + j;
                x[0] = b0; x[2560] = b1; x[5120] = b2;
            } else {
                u16* x = o1 + (size_t)b * 7680 + 1536 + j;
                x[0] = b0; x[2560] = b1; x[5120] = b2;
                u16* hh = o2 + ((size_t)b * T + t) * 3072 + j;
                hh[0] = b0; hh[1024] = b1; hh[2048] = b2;
            }
        }
    }
}

// ---------------------------------------------------------------------------
// Attention body (one block per b, 256 threads). f16 mW. Writes x3 attn triple.
// Region loops unrolled 2-wide for load ILP (1 block/CU occupancy in step_k1).
// ---------------------------------------------------------------------------
__device__ __forceinline__ void attn_body(
    int b, const float* __restrict__ qbuf,
    const u16* __restrict__ img_mW, const u16* __restrict__ ppl_mW,
    const float* __restrict__ img_v, const float* __restrict__ ppl_v,
    const float* __restrict__ img_feats, const float* __restrict__ ppl_feats,
    u16* __restrict__ x3_out, float* smf)
{
    const int tid = threadIdx.x, lane = tid & 63, wv = tid >> 6;
    float* qs  = smf;
    float* vs  = smf + 2048;
    float* aw  = smf + 4096;
    float* awn = smf + 4352;

    for (int i = tid; i < 2048; i += 256) {
        qs[i] = qbuf[(size_t)b * 2048 + i];
        vs[i] = (i < 1024) ? img_v[i] : ppl_v[i - 1024];
    }
    __syncthreads();

    // img scores: regions wv, wv+4, ... (9 per wave); 2-wide unroll
    for (int n0 = wv; n0 < NI; n0 += 8) {
        const int n1 = n0 + 4;
        const u16* mp0 = img_mW + ((size_t)b * NI + n0) * 1024;
        const u16* mp1 = (n1 < NI) ? img_mW + ((size_t)b * NI + n1) * 1024 : mp0;
        float s0 = 0.f, s1 = 0.f;
#pragma unroll
        for (int u = 0; u < 2; ++u) {
            const int h = (lane + 64 * u) * 8;
            const us8 m80 = *(const us8*)(mp0 + h);
            const us8 m81 = *(const us8*)(mp1 + h);
#pragma unroll
            for (int j = 0; j < 8; ++j) {
                s0 += tanhf(qs[h + j] + h2f(m80[j])) * vs[h + j];
                s1 += tanhf(qs[h + j] + h2f(m81[j])) * vs[h + j];
            }
        }
        for (int o = 1; o < 64; o <<= 1) { s0 += __shfl_xor(s0, o, 64); s1 += __shfl_xor(s1, o, 64); }
        if (lane == 0) { aw[n0] = s0; if (n1 < NI) aw[n1] = s1; }
    }
    // ppl scores: 25 per wave; 2-wide unroll
    for (int n0 = wv; n0 < NP; n0 += 8) {
        const int n1 = n0 + 4;
        const u16* mp0 = ppl_mW + ((size_t)b * NP + n0) * 1024;
        const u16* mp1 = (n1 < NP) ? ppl_mW + ((size_t)b * NP + n1) * 1024 : mp0;
        float s0 = 0.f, s1 = 0.f;
#pragma unroll
        for (int u = 0; u < 2; ++u) {
            const int h = (lane + 64 * u) * 8;
            const us8 m80 = *(const us8*)(mp0 + h);
            const us8 m81 = *(const us8*)(mp1 + h);
#pragma unroll
            for (int j = 0; j < 8; ++j) {
                s0 += tanhf(qs[1024 + h + j] + h2f(m80[j])) * vs[1024 + h + j];
                s1 += tanhf(qs[1024 + h + j] + h2f(m81[j])) * vs[1024 + h + j];
            }
        }
        for (int o = 1; o < 64; o <<= 1) { s0 += __shfl_xor(s0, o, 64); s1 += __shfl_xor(s1, o, 64); }
        if (lane == 0) { aw[36 + n0] = s0; if (n1 < NP) aw[36 + n1] = s1; }
    }
    __syncthreads();

    if (wv == 0) {
        const float x = (lane < NI) ? aw[lane] : -3.4e38f;
        float mx = x;
        for (int o = 1; o < 64; o <<= 1) mx = fmaxf(mx, __shfl_xor(mx, o, 64));
        const float e = (lane < NI) ? expf(x - mx) : 0.f;
        float ss = e;
        for (int o = 1; o < 64; o <<= 1) ss += __shfl_xor(ss, o, 64);
        if (lane < NI) awn[lane] = e / ss;
    } else if (wv == 1) {
        const float x0 = aw[36 + lane];
        const float x1 = (lane < NP - 64) ? aw[100 + lane] : -3.4e38f;
        float mx = fmaxf(x0, x1);
        for (int o = 1; o < 64; o <<= 1) mx = fmaxf(mx, __shfl_xor(mx, o, 64));
        const float e0 = expf(x0 - mx);
        const float e1 = (lane < NP - 64) ? expf(x1 - mx) : 0.f;
        float ss = e0 + e1;
        for (int o = 1; o < 64; o <<= 1) ss += __shfl_xor(ss, o, 64);
        awn[36 + lane] = e0 / ss;
        if (lane < NP - 64) awn[100 + lane] = e1 / ss;
    }
    __syncthreads();

#pragma unroll
    for (int dd = 0; dd < 2; ++dd) {
        const int d = tid + dd * 256;
        float s = 0.f;
        const float* ip = img_feats + (size_t)b * NI * 512 + d;
#pragma unroll 4
        for (int n = 0; n < NI; ++n) s += awn[n] * ip[n * 512];
        const float* pp = ppl_feats + (size_t)b * NP * 512 + d;
#pragma unroll 4
        for (int n = 0; n < NP; ++n) s += awn[36 + n] * pp[n * 512];
        u16 b0, b1, b2; split1<false>(s, b0, b1, b2);
        u16* o = x3_out + (size_t)b * 7680 + d;
        o[0] = b0; o[2560] = b1; o[5120] = b2;
    }
}

// ---------------------------------------------------------------------------
// K1(t): blocks [0,128) attn(t-1) (skip t==0); [128,256) vis(t) (skip t==T).
// BK=384 -> 96 KB LDS, 1 block/CU.
// ---------------------------------------------------------------------------
__global__ __launch_bounds__(256)
void step_k1(const float* __restrict__ qbuf,
             const u16* __restrict__ img_mW, const u16* __restrict__ ppl_mW,
             const float* __restrict__ img_v, const float* __restrict__ ppl_v,
             const float* __restrict__ img_feats, const float* __restrict__ ppl_feats,
             u16* x3_prev,
             const u16* __restrict__ vis_A, const u16* __restrict__ visWhh3,
             const float* __restrict__ g_pre_t, float* c_vis,
             u16* a3_new, u16* x3_cur, int t)
{
    __shared__ __align__(16) u16 smem[2 * 64 * 384];   // 96 KB
    const int blk = blockIdx.x;
    if (blk < 128) {
        if (t >= 1)
            attn_body(blk, qbuf, img_mW, ppl_mW, img_v, ppl_v,
                      img_feats, ppl_feats, x3_prev, (float*)smem);
    } else {
        if (t < T)
            gemm_core<1, 64, 384>(smem, smem + 64 * 384, vis_A, visWhh3,
                                  g_pre_t, nullptr, c_vis, a3_new, x3_cur,
                                  G4, 3072, t, (blk - 128) & 63, (blk - 128) >> 6);
    }
}

// ---------------------------------------------------------------------------
// K2(t): blocks [0,128) q(t) (skip t==T); [128,256) lang(t-1) (skip t==0).
// BK=384 -> 96 KB LDS, 1 block/CU.
// ---------------------------------------------------------------------------
__global__ __launch_bounds__(256)
void step_k2(const u16* __restrict__ a3_new, const u16* __restrict__ wq3t,
             float* qbuf,
             const u16* __restrict__ lang_A, const u16* __restrict__ langW3,
             const float* __restrict__ lang_bi, float* c_lang,
             u16* lang_o1, u16* h3_all, int t)
{
    __shared__ __align__(16) u16 smem[2 * 64 * 384];   // 96 KB
    const int blk = blockIdx.x;
    if (blk < 128) {
        if (t < T)
            gemm_core<0, 32, 384>(smem, smem + 64 * 384, a3_new, wq3t,
                                  nullptr, nullptr, qbuf, nullptr, nullptr,
                                  2048, 3072, t, blk & 63, blk >> 6);
    } else {
        if (t >= 1)
            gemm_core<2, 64, 384>(smem, smem + 64 * 384, lang_A, langW3,
                                  nullptr, lang_bi, c_lang, lang_o1, h3_all,
                                  G4, 7680, t - 1, (blk - 128) & 63, (blk - 128) >> 6);
    }
}

// ---------------------------------------------------------------------------
// Row-major split: src f32 [M][ld] -> triple cols in out [M][3*Kt].
template<bool WSIDE>
__global__ __launch_bounds__(256)
void split3_rows(const float* __restrict__ src, int ld, int K8,
                 u16* __restrict__ out, int Kt, int coloff)
{
    const int idx = blockIdx.x * 256 + threadIdx.x;
    const int r = idx / K8, kk = (idx - r * K8) * 8;
    const float* s = src + (size_t)r * ld + kk;
    const float4 x0 = *(const float4*)s, x1 = *(const float4*)(s + 4);
    float xs[8] = {x0.x, x0.y, x0.z, x0.w, x1.x, x1.y, x1.z, x1.w};
    us8 h, m, l;
#pragma unroll
    for (int j = 0; j < 8; ++j) { u16 a, b, c; split1<WSIDE>(xs[j], a, b, c); h[j]=a; m[j]=b; l[j]=c; }
    u16* o = out + (size_t)r * (3 * Kt) + coloff + kk;
    *(us8*)o = h; *(us8*)(o + Kt) = m; *(us8*)(o + 2 * Kt) = l;
}

// LSTM weight split, gate-interleaved output rows: src row r = g*1024+j ->
// out row (j>>4)*64 + g*16 + (j&15). W-side triple.
__global__ __launch_bounds__(256)
void split3_lstm(const float* __restrict__ src, int ld, int K8,
                 u16* __restrict__ out, int Kt, int coloff)
{
    const int idx = blockIdx.x * 256 + threadIdx.x;
    const int r = idx / K8, kk = (idx - r * K8) * 8;
    const int g = r >> 10, j = r & 1023;
    const int orow = ((j >> 4) << 6) + (g << 4) + (j & 15);
    const float* s = src + (size_t)r * ld + kk;
    const float4 x0 = *(const float4*)s, x1 = *(const float4*)(s + 4);
    float xs[8] = {x0.x, x0.y, x0.z, x0.w, x1.x, x1.y, x1.z, x1.w};
    us8 h, m, l;
#pragma unroll
    for (int jj = 0; jj < 8; ++jj) { u16 a, b, c; split1<true>(xs[jj], a, b, c); h[jj]=a; m[jj]=b; l[jj]=c; }
    u16* o = out + (size_t)orow * (3 * Kt) + coloff + kk;
    *(us8*)o = h; *(us8*)(o + Kt) = m; *(us8*)(o + 2 * Kt) = l;
}

// bias permute into gate-interleaved col space
__global__ __launch_bounds__(256)
void permute_bias_lstm(const float* __restrict__ b, float* __restrict__ out)
{
    const int c = blockIdx.x * 256 + threadIdx.x;
    const int jg = c >> 6, g = (c >> 4) & 3, jlo = c & 15;
    out[c] = b[g * 1024 + jg * 16 + jlo];
}

// Transpose + W-side split: W f32 [K][N] -> out u16 [N][3K].
__global__ __launch_bounds__(256)
void transpose_split3_w(const float* __restrict__ W, int N, int K,
                        u16* __restrict__ out)
{
    const int n0 = blockIdx.x * 64, k0 = blockIdx.y * 64;
    const int tid = threadIdx.x;
    __shared__ float ts[64][65];
    for (int i = 0; i < 16; ++i) {
        const int idx = i * 256 + tid;
        const int kl = idx >> 6, nl = idx & 63;
        float v = 0.f;
        if (n0 + nl < N) v = W[(size_t)(k0 + kl) * N + n0 + nl];
        ts[nl][kl] = v;
    }
    __syncthreads();
    for (int i = 0; i < 2; ++i) {
        const int idx = i * 256 + tid;
        const int nl = idx >> 3, kc = (idx & 7) * 8;
        if (n0 + nl < N) {
            us8 h, m, l;
#pragma unroll
            for (int j = 0; j < 8; ++j) {
                u16 a, b, c; split1<true>(ts[nl][kc + j], a, b, c);
                h[j] = a; m[j] = b; l[j] = c;
            }
            u16* o = out + (size_t)(n0 + nl) * (3 * K) + k0 + kc;
            *(us8*)o = h; *(us8*)(o + K) = m; *(us8*)(o + 2 * K) = l;
        }
    }
}

// embedding lookup + relu + A-side split -> A2 rows [T*B][3072], demb segment
// at coloff 512 of a Kt=1024 triple ([pool(0:512) | demb(512:1024)]).
__global__ __launch_bounds__(256)
void embed_relu3(const int* __restrict__ question, const float* __restrict__ emb,
                 u16* __restrict__ A2)
{
    const int idx = blockIdx.x * 256 + threadIdx.x;
    const int r = idx >> 6, kk = (idx & 63) * 8;
    const int t = r / B, b = r - t * B;
    const int tok = (t == 0) ? SOS : question[b * T + t - 1];
    const float* s = emb + (size_t)tok * DW + kk;
    const float4 x0 = *(const float4*)s, x1 = *(const float4*)(s + 4);
    float xs[8] = {x0.x, x0.y, x0.z, x0.w, x1.x, x1.y, x1.z, x1.w};
    us8 h, m, l;
#pragma unroll
    for (int j = 0; j < 8; ++j) {
        u16 a, b2, c; split1<false>(fmaxf(xs[j], 0.f), a, b2, c);
        h[j] = a; m[j] = b2; l[j] = c;
    }
    u16* o = A2 + (size_t)r * 3072 + 512 + kk;
    *(us8*)o = h; *(us8*)(o + 1024) = m; *(us8*)(o + 2048) = l;
}

// pool attention scores (f32 mW)
__global__ __launch_bounds__(256)
void attn_score(const float* __restrict__ q, int qld,
                const float* __restrict__ mW, const float* __restrict__ v,
                float* __restrict__ score, int Nn, int Hd)
{
    const int n = blockIdx.x, b = blockIdx.y;
    const float* qp = q + (size_t)b * qld;
    const float* mp = mW + ((size_t)b * Nn + n) * Hd;
    float s = 0.f;
    for (int h = threadIdx.x; h < Hd; h += 256)
        s += tanhf(qp[h] + mp[h]) * v[h];
    __shared__ float red[4];
    const int lane = threadIdx.x & 63, wv = threadIdx.x >> 6;
    for (int o = 32; o; o >>= 1) s += __shfl_down(s, o, 64);
    if (lane == 0) red[wv] = s;
    __syncthreads();
    if (threadIdx.x == 0) score[(size_t)b * Nn + n] = red[0] + red[1] + red[2] + red[3];
}

// pool ctx -> broadcast triple into A2 pool segment (coloff 0) for all T rows
__global__ __launch_bounds__(256)
void attn_ctx_pool(const float* __restrict__ score, const float* __restrict__ m,
                   u16* __restrict__ A2, int Nn)
{
    constexpr int D = 512;
    const int b = blockIdx.x;
    __shared__ float aw[128];
    __shared__ float red[8];
    const int tid = threadIdx.x, lane = tid & 63, wv = tid >> 6;
    float mx = -3.4e38f;
    for (int n = tid; n < Nn; n += 256) mx = fmaxf(mx, score[(size_t)b * Nn + n]);
    for (int o = 32; o; o >>= 1) mx = fmaxf(mx, __shfl_down(mx, o, 64));
    if (lane == 0) red[wv] = mx;
    __syncthreads();
    mx = fmaxf(fmaxf(red[0], red[1]), fmaxf(red[2], red[3]));
    float se = 0.f;
    for (int n = tid; n < Nn; n += 256) {
        float e = expf(score[(size_t)b * Nn + n] - mx);
        aw[n] = e; se += e;
    }
    for (int o = 32; o; o >>= 1) se += __shfl_down(se, o, 64);
    if (lane == 0) red[4 + wv] = se;
    __syncthreads();
    const float inv = 1.0f / (red[4] + red[5] + red[6] + red[7]);
    for (int d = tid; d < D; d += 256) {
        float s = 0.f;
        for (int n = 0; n < Nn; ++n) s += aw[n] * m[((size_t)b * Nn + n) * D + d];
        s *= inv;
        u16 b0, b1, b2; split1<false>(s, b0, b1, b2);
        for (int tt = 0; tt < T; ++tt) {
            u16* o = A2 + ((size_t)tt * B + b) * 3072 + d;
            o[0] = b0; o[1024] = b1; o[2048] = b2;
        }
    }
}

__global__ __launch_bounds__(256)
void zero_f(float* __restrict__ p) { p[blockIdx.x * 256 + threadIdx.x] = 0.f; }

__global__ __launch_bounds__(256)
void zero_u32(unsigned int* __restrict__ p) { p[blockIdx.x * 256 + threadIdx.x] = 0u; }

// online log_softmax over out rows [r][V], argmax -> out[BTV+r]
__global__ __launch_bounds__(256)
void logsm_argmax(float* __restrict__ out)
{
    const int r = blockIdx.x;
    float* row = out + (size_t)r * V;
    const int tid = threadIdx.x, lane = tid & 63, wv = tid >> 6;
    float m = -3.4e38f, s = 0.f; int mi = 0;
    for (int i4 = tid; i4 < V / 4; i4 += 256) {
        const float4 x4 = ((const float4*)row)[i4];
        const float xs[4] = {x4.x, x4.y, x4.z, x4.w};
#pragma unroll
        for (int j = 0; j < 4; ++j) {
            const float x = xs[j];
            if (x > m) { s = s * expf(m - x) + 1.f; m = x; mi = i4 * 4 + j; }
            else       s += expf(x - m);
        }
    }
    for (int o = 1; o < 64; o <<= 1) {
        const float m2 = __shfl_xor(m, o, 64);
        const float s2 = __shfl_xor(s, o, 64);
        const int  mi2 = __shfl_xor(mi, o, 64);
        if (m2 > m || (m2 == m && mi2 < mi)) { s = s2 + s * expf(m - m2); m = m2; mi = mi2; }
        else s += s2 * expf(m2 - m);
    }
    __shared__ float sm[4], ssm[4]; __shared__ int smi[4];
    __shared__ float lse_sh; __shared__ int mi_sh;
    if (lane == 0) { sm[wv] = m; ssm[wv] = s; smi[wv] = mi; }
    __syncthreads();
    if (tid == 0) {
        float M = sm[0], S = ssm[0]; int MI = smi[0];
        for (int w = 1; w < 4; ++w) {
            if (sm[w] > M || (sm[w] == M && smi[w] < MI)) { S = ssm[w] + S * expf(M - sm[w]); M = sm[w]; MI = smi[w]; }
            else S += ssm[w] * expf(sm[w] - M);
        }
        lse_sh = M + logf(S); mi_sh = MI;
    }
    __syncthreads();
    const float lse = lse_sh;
    for (int i4 = tid; i4 < V / 4; i4 += 256) {
        float4 x4 = ((const float4*)row)[i4];
        x4.x -= lse; x4.y -= lse; x4.z -= lse; x4.w -= lse;
        ((float4*)row)[i4] = x4;
    }
    if (tid == 0) out[(size_t)B * T * V + r] = (float)mi_sh;
}

// ---------------------------------------------------------------------------
extern "C" void kernel_launch(void* const* d_in, const int* in_sizes, int n_in,
                              void* d_out, int out_size, void* d_ws, size_t ws_size,
                              hipStream_t stream)
{
    (void)in_sizes; (void)n_in; (void)out_size; (void)ws_size;

    const float* img_feats   = (const float*)d_in[0];
    const float* ppl_feats   = (const float*)d_in[1];
    const float* answer_hint = (const float*)d_in[2];
    const int*   question    = (const int*)d_in[3];
    const float* emb         = (const float*)d_in[4];
    const float* pool_Wq     = (const float*)d_in[5];
    const float* pool_Wm     = (const float*)d_in[6];
    const float* pool_b      = (const float*)d_in[7];
    const float* pool_v      = (const float*)d_in[8];
    const float* img_Wq      = (const float*)d_in[9];
    const float* img_Wm      = (const float*)d_in[10];
    const float* img_b       = (const float*)d_in[11];
    const float* img_v       = (const float*)d_in[12];
    const float* ppl_Wq      = (const float*)d_in[13];
    const float* ppl_Wm      = (const float*)d_in[14];
    const float* ppl_b       = (const float*)d_in[15];
    const float* ppl_v       = (const float*)d_in[16];
    const float* vis_Wih     = (const float*)d_in[17];
    const float* vis_Whh     = (const float*)d_in[18];
    const float* vis_b       = (const float*)d_in[19];
    const float* lang_Wih    = (const float*)d_in[20];
    const float* lang_Whh    = (const float*)d_in[21];
    const float* lang_b      = (const float*)d_in[22];
    const float* proj_W      = (const float*)d_in[23];
    const float* proj_b      = (const float*)d_in[24];

    float* out = (float*)d_out;
    float* ws  = (float*)d_ws;

    size_t off = 0;
    auto alloc = [&](size_t nf) { size_t r = off; off += (nf + 63) & ~(size_t)63; return r; };
    // Region X: dead after the decode loop; projW3t overlaid post-loop.
    const size_t regionX = off;
    float* g_pre   = ws + alloc((size_t)T * B * G4);
    float* pool_mW = ws + alloc((size_t)B * NI * DW);
    u16*   A2      = (u16*)(ws + alloc((size_t)T * B * 3072 / 2));   // [pool|demb] triple
    u16*   hint3   = (u16*)(ws + alloc((size_t)B * 1536 / 2));
    u16*   poolWq3t= (u16*)(ws + alloc((size_t)512 * 1536 / 2));
    u16*   poolWm3t= (u16*)(ws + alloc((size_t)512 * 1536 / 2));
    u16*   visWih3 = (u16*)(ws + alloc((size_t)G4 * 3072 / 2));      // interleaved rows
    u16*   img_mW  = (u16*)(ws + alloc((size_t)B * NI * H / 2));     // f16, dead post-loop
    u16*   ppl_mW  = (u16*)(ws + alloc((size_t)B * NP * H / 2));     // f16, dead post-loop
    u16*   img3    = (u16*)(ws + alloc((size_t)B * NI * 1536 / 2));
    u16*   ppl3    = (u16*)(ws + alloc((size_t)B * NP * 1536 / 2));
    // persistent beyond overlay reach
    u16* visWhh3   = (u16*)(ws + alloc((size_t)G4 * 3072 / 2));
    u16* langW3    = (u16*)(ws + alloc((size_t)G4 * 7680 / 2));
    u16* wq3t      = (u16*)(ws + alloc((size_t)2048 * 3072 / 2));
    u16* imgWm3t   = (u16*)(ws + alloc((size_t)1024 * 1536 / 2));
    u16* pplWm3t   = (u16*)(ws + alloc((size_t)1024 * 1536 / 2));
    float* c_vis   = ws + alloc((size_t)B * H);
    float* c_lang  = ws + alloc((size_t)B * H);
    u16* a3        = (u16*)(ws + alloc((size_t)2 * B * 3072 / 2));   // dbuf, contiguous with x3
    u16* x3        = (u16*)(ws + alloc((size_t)2 * B * 7680 / 2));
    u16* h3_all    = (u16*)(ws + alloc((size_t)B * T * 3072 / 2));
    float* qbuf    = ws + alloc((size_t)B * 2048);
    float* vis_bi  = ws + alloc((size_t)G4);
    float* lang_bi = ws + alloc((size_t)G4);
    float* pool_qW = ws + alloc((size_t)B * DW);
    float* pool_sc = ws + alloc((size_t)B * NI);
    u16* projW3t   = (u16*)(ws + regionX);   // overlay over dead region

    const dim3 blk(256);

    // ---- init state ----
    zero_f<<<dim3((2 * B * H) / 256), blk, 0, stream>>>(c_vis);
    zero_u32<<<dim3((2 * B * 3072 + 2 * B * 7680) / 2 / 256), blk, 0, stream>>>((unsigned int*)a3);

    // ---- one-time splits / transposes ----
    embed_relu3<<<dim3(T * B * 64 / 256), blk, 0, stream>>>(question, emb, A2);
    permute_bias_lstm<<<dim3(16), blk, 0, stream>>>(vis_b, vis_bi);
    permute_bias_lstm<<<dim3(16), blk, 0, stream>>>(lang_b, lang_bi);
    split3_lstm<<<dim3(G4 * 128 / 256), blk, 0, stream>>>(vis_Wih, 1024, 128, visWih3, 1024, 0);
    split3_lstm<<<dim3(G4 * 128 / 256), blk, 0, stream>>>(vis_Whh, 1024, 128, visWhh3, 1024, 0);
    split3_lstm<<<dim3(G4 * 192 / 256), blk, 0, stream>>>(lang_Wih, 1536, 192, langW3, 2560, 0);
    split3_lstm<<<dim3(G4 * 128 / 256), blk, 0, stream>>>(lang_Whh, 1024, 128, langW3, 2560, 1536);
    split3_rows<false><<<dim3(B * NI * 64 / 256), blk, 0, stream>>>(img_feats, 512, 64, img3, 512, 0);
    split3_rows<false><<<dim3(B * NP * 64 / 256), blk, 0, stream>>>(ppl_feats, 512, 64, ppl3, 512, 0);
    split3_rows<false><<<dim3(B * 64 / 256), blk, 0, stream>>>(answer_hint, 512, 64, hint3, 512, 0);
    transpose_split3_w<<<dim3(8, 8), blk, 0, stream>>>(pool_Wq, 512, 512, poolWq3t);
    transpose_split3_w<<<dim3(8, 8), blk, 0, stream>>>(pool_Wm, 512, 512, poolWm3t);
    transpose_split3_w<<<dim3(16, 8), blk, 0, stream>>>(img_Wm, 1024, 512, imgWm3t);
    transpose_split3_w<<<dim3(16, 8), blk, 0, stream>>>(ppl_Wm, 1024, 512, pplWm3t);
    transpose_split3_w<<<dim3(16, 16), blk, 0, stream>>>(img_Wq, 1024, 1024, wq3t);
    transpose_split3_w<<<dim3(16, 16), blk, 0, stream>>>(ppl_Wq, 1024, 1024, wq3t + (size_t)1024 * 3072);

    // ---- precompute ----
    gemm3<64, 64, false, false><<<dim3(8, 2), blk, 0, stream>>>(hint3, poolWq3t, nullptr, nullptr, pool_qW, 512, 1536);
    gemm3<128, 128, false, true><<<dim3(4, 36), blk, 0, stream>>>(img3, poolWm3t, nullptr, pool_b, pool_mW, 512, 1536);
    attn_score<<<dim3(NI, B), blk, 0, stream>>>(pool_qW, 512, pool_mW, pool_v, pool_sc, NI, 512);
    attn_ctx_pool<<<dim3(B), blk, 0, stream>>>(pool_sc, img_feats, A2, NI);
    // g_pre = A2 @ visWih3^T + vis_b  (single fused GEMM, K3=3072)
    gemm3<128, 128, false, true><<<dim3(32, 20), blk, 0, stream>>>(A2, visWih3, nullptr, vis_bi, g_pre, G4, 3072);
    // attention memories -> f16 (+bias folded)
    gemm3<128, 128, false, true, 0, true><<<dim3(8, 36), blk, 0, stream>>>(img3, imgWm3t, nullptr, img_b, img_mW, H, 1536);
    gemm3<128, 128, false, true, 0, true><<<dim3(8, 100), blk, 0, stream>>>(ppl3, pplWm3t, nullptr, ppl_b, ppl_mW, H, 1536);

    // ---- sequential decode: K1(t)=[attn(t-1) || vis(t)], K2(t)=[q(t) || lang(t-1)] ----
    for (int t = 0; t <= T; ++t) {
        u16* x3_prev = x3 + (size_t)((t + 1) & 1) * B * 7680;   // x3(t-1)
        u16* x3_cur  = x3 + (size_t)(t & 1) * B * 7680;         // x3(t)
        u16* vis_Ain = a3 + (size_t)(t & 1) * B * 3072;         // h_vis(t-1) triple
        u16* a3_new  = a3 + (size_t)((t + 1) & 1) * B * 3072;   // h_vis(t) triple
        const float* gp = g_pre + (size_t)(t < T ? t : 0) * B * G4;
        step_k1<<<dim3(256), blk, 0, stream>>>(
            qbuf, img_mW, ppl_mW, img_v, ppl_v, img_feats, ppl_feats, x3_prev,
            vis_Ain, visWhh3, gp, c_vis, a3_new, x3_cur, t);
        step_k2<<<dim3(256), blk, 0, stream>>>(
            a3_new, wq3t, qbuf, x3_prev, langW3, lang_bi, c_lang,
            x3_cur, h3_all, t);
    }

    // ---- deferred projection (super-tiled for L3 reuse) ----
    transpose_split3_w<<<dim3(313, 16), blk, 0, stream>>>(proj_W, V, 1024, projW3t);
    gemm3<128, 128, false, true, 20><<<dim3(157, 20), blk, 0, stream>>>(
        h3_all, projW3t, nullptr, proj_b, out, V, 3072);
    logsm_argmax<<<dim3(B * T), blk, 0, stream>>>(out);
}

// Round 10
// 3579.265 us; speedup vs baseline: 1.1554x; 1.1554x over previous
//
#include <hip/hip_runtime.h>
#include <cstddef>
#include <cstdint>

using u16 = unsigned short;
typedef float    f32x4 __attribute__((ext_vector_type(4)));
typedef _Float16 f16x8 __attribute__((ext_vector_type(8)));
typedef u16      us8   __attribute__((ext_vector_type(8)));

constexpr int B  = 128;
constexpr int T  = 20;
constexpr int V  = 20000;
constexpr int DW = 512;
constexpr int H  = 1024;
constexpr int G4 = 4096;
constexpr int NI = 36;
constexpr int NP = 100;
constexpr int SOS = 1;

__device__ __forceinline__ float sigf(float x) { return 1.0f / (1.0f + expf(-x)); }
__device__ __forceinline__ u16 f16bits(_Float16 h) { u16 u; __builtin_memcpy(&u, &h, 2); return u; }
__device__ __forceinline__ float h2f(u16 u) { _Float16 h; __builtin_memcpy(&h, &u, 2); return (float)h; }

// f16x3 split: x ~= hi + lo as triples; one K-expanded f16 GEMM computes
// hi*hi + lo*hi + hi*lo (error ~2^-22). A: [hi, lo*64, hi/64]; W: [hi, hi/64, lo*64]
template<bool WSIDE>
__device__ __forceinline__ void split1(float x, u16& b0, u16& b1, u16& b2) {
    _Float16 h  = (_Float16)x;
    float    hf = (float)h;
    _Float16 lo = (_Float16)((x - hf) * 64.0f);
    _Float16 hs = (_Float16)(hf * (1.0f / 64.0f));
    b0 = f16bits(h);
    if constexpr (WSIDE) { b1 = f16bits(hs); b2 = f16bits(lo); }
    else                 { b1 = f16bits(lo); b2 = f16bits(hs); }
}

// ---------------------------------------------------------------------------
// Generic MFMA GEMM (precompute + proj): C[M,N] = A3[M,K3] x B3t[N,K3]^T.
// BK=64, 4 waves 2x2, software-pipelined. NSW>0: super-tile remap for L3 reuse.
// OUTF16: write C as f16.
// ---------------------------------------------------------------------------
template<int BM, int BN, bool HAS_ADD, bool HAS_BIAS, int NSW = 0, bool OUTF16 = false>
__global__ __launch_bounds__(256)
void gemm3(const u16* __restrict__ A, const u16* __restrict__ Bt,
           const float* __restrict__ Add, const float* __restrict__ bias,
           void* __restrict__ Cv, int N, int K3)
{
    __shared__ __align__(16) u16 As[BM * 64];
    __shared__ __align__(16) u16 Bs[BN * 64];
    constexpr int FR = BM / 32, FC = BN / 32, PA = BM / 32, PB = BN / 32;
    const int tid  = threadIdx.x;
    int bx = blockIdx.x, by = blockIdx.y;
    if constexpr (NSW > 0) {
        const int nt = (int)gridDim.x, mt = (int)gridDim.y;
        const int lin = by * nt + bx;
        const int sc0 = (lin / (NSW * mt)) * NSW;
        const int w   = (NSW < nt - sc0) ? NSW : (nt - sc0);
        const int r   = lin - sc0 * mt;
        bx = sc0 + r % w;
        by = r / w;
    }
    const int bm   = by * BM, bn = bx * BN;
    const int lane = tid & 63, wid = tid >> 6;
    const int wm   = (wid >> 1) * (BM / 2), wn = (wid & 1) * (BN / 2);
    const int srow = tid >> 3;
    const int scol = (tid & 7) * 8;

    f32x4 acc[FR][FC] = {};
    us8 ra[PA], rb[PB];

    auto ldg = [&](int k0) {
#pragma unroll
        for (int p = 0; p < PA; ++p)
            ra[p] = *(const us8*)(A + (size_t)(bm + p * 32 + srow) * K3 + k0 + scol);
#pragma unroll
        for (int p = 0; p < PB; ++p) {
            int n = bn + p * 32 + srow; if (n > N - 1) n = N - 1;
            rb[p] = *(const us8*)(Bt + (size_t)n * K3 + k0 + scol);
        }
    };
    ldg(0);

    for (int k0 = 0; k0 < K3; k0 += 64) {
        __syncthreads();
#pragma unroll
        for (int p = 0; p < PA; ++p) {
            const int row = p * 32 + srow;
            *(us8*)((char*)As + row * 128 + ((scol * 2) ^ ((row & 7) << 4))) = ra[p];
        }
#pragma unroll
        for (int p = 0; p < PB; ++p) {
            const int row = p * 32 + srow;
            *(us8*)((char*)Bs + row * 128 + ((scol * 2) ^ ((row & 7) << 4))) = rb[p];
        }
        __syncthreads();
        if (k0 + 64 < K3) ldg(k0 + 64);
#pragma unroll
        for (int ks = 0; ks < 2; ++ks) {
            f16x8 af[FR], bf[FC];
#pragma unroll
            for (int m = 0; m < FR; ++m) {
                const int row = wm + m * 16 + (lane & 15);
                const int cb  = (ks * 64 + ((lane >> 4) << 4)) ^ ((row & 7) << 4);
                af[m] = *(const f16x8*)((const char*)As + row * 128 + cb);
            }
#pragma unroll
            for (int n = 0; n < FC; ++n) {
                const int row = wn + n * 16 + (lane & 15);
                const int cb  = (ks * 64 + ((lane >> 4) << 4)) ^ ((row & 7) << 4);
                bf[n] = *(const f16x8*)((const char*)Bs + row * 128 + cb);
            }
#pragma unroll
            for (int m = 0; m < FR; ++m)
#pragma unroll
                for (int n = 0; n < FC; ++n)
                    acc[m][n] = __builtin_amdgcn_mfma_f32_16x16x32_f16(af[m], bf[n], acc[m][n], 0, 0, 0);
        }
    }
#pragma unroll
    for (int m = 0; m < FR; ++m) {
        const int r0 = bm + wm + m * 16 + ((lane >> 4) << 2);
#pragma unroll
        for (int n = 0; n < FC; ++n) {
            const int c = bn + wn + n * 16 + (lane & 15);
            if (c < N) {
#pragma unroll
                for (int j = 0; j < 4; ++j) {
                    float v = acc[m][n][j];
                    if constexpr (HAS_ADD)  v += Add[(size_t)(r0 + j) * N + c];
                    if constexpr (HAS_BIAS) v += bias[c];
                    if constexpr (OUTF16)
                        ((u16*)Cv)[(size_t)(r0 + j) * N + c] = f16bits((_Float16)v);
                    else
                        ((float*)Cv)[(size_t)(r0 + j) * N + c] = v;
                }
            }
        }
    }
}

// ---------------------------------------------------------------------------
// In-loop GEMM core (BM=64, BN/BK params), 256 threads, 4 waves each 16 rows x
// BN cols. EPI=0: plain f32 C. EPI=1: vis-LSTM epilogue. EPI=2: lang-LSTM.
// ---------------------------------------------------------------------------
template<int EPI, int BN, int BK>
__device__ __forceinline__ void gemm_core(
    u16* As, u16* Bs,
    const u16* A, const u16* Bt,
    const float* Add, const float* bias,
    float* CS, u16* o1, u16* o2,
    int N, int K3, int t, int bx, int by)
{
    constexpr int NA8  = BK / 32;
    constexpr int TPRB = 256 / BN;
    constexpr int NB8  = (BK / TPRB) / 8;
    constexpr int NFC  = BN / 16;
    const int tid  = threadIdx.x;
    const int bn   = bx * BN, bm = by * 64;
    const int lane = tid & 63, wv = tid >> 6;
    const int rowA = tid >> 2;
    const int scA  = (tid & 3) * (BK / 4);
    const int rowB = tid / TPRB;
    const int scB  = (tid % TPRB) * (BK / TPRB);
    const int swzA = (rowA & 7) << 4;
    const int swzB = (rowB & 7) << 4;
    const u16* Ap = A  + (size_t)(bm + rowA) * K3 + scA;
    const u16* Bp = Bt + (size_t)(bn + rowB) * K3 + scB;
    char* Awp = (char*)As + rowA * (BK * 2);
    char* Bwp = (char*)Bs + rowB * (BK * 2);
    const int arow = wv * 16 + (lane & 15);
    const char* Arp = (const char*)As + arow * (BK * 2);
    const int aswz = (arow & 7) << 4;
    const int jl   = lane & 15;

    f32x4 acc[NFC] = {};
    us8 ra[NA8], rb[NB8];
#pragma unroll
    for (int i = 0; i < NA8; ++i) ra[i] = *(const us8*)(Ap + 8 * i);
#pragma unroll
    for (int i = 0; i < NB8; ++i) rb[i] = *(const us8*)(Bp + 8 * i);

    for (int k0 = 0; k0 < K3; k0 += BK) {
        __syncthreads();
#pragma unroll
        for (int i = 0; i < NA8; ++i)
            *(us8*)(Awp + ((scA * 2 + 16 * i) ^ swzA)) = ra[i];
#pragma unroll
        for (int i = 0; i < NB8; ++i)
            *(us8*)(Bwp + ((scB * 2 + 16 * i) ^ swzB)) = rb[i];
        __syncthreads();
        if (k0 + BK < K3) {
#pragma unroll
            for (int i = 0; i < NA8; ++i) ra[i] = *(const us8*)(Ap + k0 + BK + 8 * i);
#pragma unroll
            for (int i = 0; i < NB8; ++i) rb[i] = *(const us8*)(Bp + k0 + BK + 8 * i);
        }
#pragma unroll
        for (int ks = 0; ks < BK / 32; ++ks) {
            const int cb = ks * 64 + ((lane >> 4) << 4);
            const f16x8 af = *(const f16x8*)(Arp + (cb ^ aswz));
#pragma unroll
            for (int g = 0; g < NFC; ++g) {
                const int brow = g * 16 + jl;
                const f16x8 bf = *(const f16x8*)((const char*)Bs + brow * (BK * 2) + (cb ^ ((brow & 7) << 4)));
                acc[g] = __builtin_amdgcn_mfma_f32_16x16x32_f16(af, bf, acc[g], 0, 0, 0);
            }
        }
    }
    const int rb0 = bm + wv * 16 + ((lane >> 4) << 2);
    if constexpr (EPI == 0) {
#pragma unroll
        for (int g = 0; g < NFC; ++g) {
            const int c = bn + g * 16 + jl;
#pragma unroll
            for (int jj = 0; jj < 4; ++jj)
                CS[(size_t)(rb0 + jj) * N + c] = acc[g][jj];
        }
    } else {
        const int j = bx * 16 + jl;
#pragma unroll
        for (int jj = 0; jj < 4; ++jj) {
            const int b = rb0 + jj;
            float gi = acc[0][jj], gf = acc[1][jj], gg = acc[2][jj], go = acc[3][jj];
            if constexpr (EPI == 1) {
                const float* ap = Add + (size_t)b * 4096 + bn + jl;
                gi += ap[0]; gf += ap[16]; gg += ap[32]; go += ap[48];
            } else {
                const float* bp = bias + bn + jl;
                gi += bp[0]; gf += bp[16]; gg += bp[32]; go += bp[48];
            }
            const float c = sigf(gf) * CS[b * 1024 + j] + sigf(gi) * tanhf(gg);
            const float h = sigf(go) * tanhf(c);
            CS[b * 1024 + j] = c;
            u16 b0, b1, b2; split1<false>(h, b0, b1, b2);
            if constexpr (EPI == 1) {
                u16* a = o1 + (size_t)b * 3072 + j;
                a[0] = b0; a[1024] = b1; a[2048] = b2;
                u16* x = o2 + (size_t)b * 7680 + 512 + j;
                x[0] = b0; x[2560] = b1; x[5120] = b2;
            } else {
                u16* x = o1 + (size_t)b * 7680 + 1536 + j;
                x[0] = b0; x[2560] = b1; x[5120] = b2;
                u16* hh = o2 + ((size_t)b * T + t) * 3072 + j;
                hh[0] = b0; hh[1024] = b1; hh[2048] = b2;
            }
        }
    }
}

// q GEMM (EPI=0, BN=16, BK=384): qbuf = a3_cur @ wq3t^T. grid (128,2) = 256 blocks.
__global__ __launch_bounds__(256)
void gemm_q(const u16* __restrict__ A, const u16* __restrict__ Bt,
            float* __restrict__ CS, int N, int K3)
{
    __shared__ __align__(16) u16 As[64 * 384];
    __shared__ __align__(16) u16 Bs[16 * 384];
    gemm_core<0, 16, 384>(As, Bs, A, Bt, nullptr, nullptr, CS, nullptr, nullptr,
                          N, K3, 0, blockIdx.x, blockIdx.y);
}

// Combined step kernel: z=0 -> lang(t-1) (skipped at t==0), z=1 -> vis(t)
// (skipped at t==T). grid (64,2,2), 256 threads, BK=384 (96 KB LDS).
__global__ __launch_bounds__(256)
void step_combo(const u16* __restrict__ lang_A, const u16* __restrict__ langW3,
                const float* __restrict__ lang_bi, float* c_lang,
                u16* lang_o1, u16* h3_all,
                const u16* __restrict__ vis_A, const u16* __restrict__ visWhh3,
                const float* __restrict__ g_pre_t, float* c_vis,
                u16* vis_o1, u16* vis_o2, int t)
{
    __shared__ __align__(16) u16 As[64 * 384];
    __shared__ __align__(16) u16 Bs[64 * 384];
    if (blockIdx.z == 0) {
        if (t >= 1)
            gemm_core<2, 64, 384>(As, Bs, lang_A, langW3, nullptr, lang_bi,
                                  c_lang, lang_o1, h3_all, G4, 7680, t - 1,
                                  blockIdx.x, blockIdx.y);
    } else {
        if (t < T)
            gemm_core<1, 64, 384>(As, Bs, vis_A, visWhh3, g_pre_t, nullptr,
                                  c_vis, vis_o1, vis_o2, G4, 3072, t,
                                  blockIdx.x, blockIdx.y);
    }
}

// ---------------------------------------------------------------------------
// Row-major split: src f32 [M][ld] -> triple cols in out [M][3*Kt].
template<bool WSIDE>
__global__ __launch_bounds__(256)
void split3_rows(const float* __restrict__ src, int ld, int K8,
                 u16* __restrict__ out, int Kt, int coloff)
{
    const int idx = blockIdx.x * 256 + threadIdx.x;
    const int r = idx / K8, kk = (idx - r * K8) * 8;
    const float* s = src + (size_t)r * ld + kk;
    const float4 x0 = *(const float4*)s, x1 = *(const float4*)(s + 4);
    float xs[8] = {x0.x, x0.y, x0.z, x0.w, x1.x, x1.y, x1.z, x1.w};
    us8 h, m, l;
#pragma unroll
    for (int j = 0; j < 8; ++j) { u16 a, b, c; split1<WSIDE>(xs[j], a, b, c); h[j]=a; m[j]=b; l[j]=c; }
    u16* o = out + (size_t)r * (3 * Kt) + coloff + kk;
    *(us8*)o = h; *(us8*)(o + Kt) = m; *(us8*)(o + 2 * Kt) = l;
}

// LSTM weight split, gate-interleaved output rows: src row r = g*1024+j ->
// out row (j>>4)*64 + g*16 + (j&15). W-side triple.
__global__ __launch_bounds__(256)
void split3_lstm(const float* __restrict__ src, int ld, int K8,
                 u16* __restrict__ out, int Kt, int coloff)
{
    const int idx = blockIdx.x * 256 + threadIdx.x;
    const int r = idx / K8, kk = (idx - r * K8) * 8;
    const int g = r >> 10, j = r & 1023;
    const int orow = ((j >> 4) << 6) + (g << 4) + (j & 15);
    const float* s = src + (size_t)r * ld + kk;
    const float4 x0 = *(const float4*)s, x1 = *(const float4*)(s + 4);
    float xs[8] = {x0.x, x0.y, x0.z, x0.w, x1.x, x1.y, x1.z, x1.w};
    us8 h, m, l;
#pragma unroll
    for (int jj = 0; jj < 8; ++jj) { u16 a, b, c; split1<true>(xs[jj], a, b, c); h[jj]=a; m[jj]=b; l[jj]=c; }
    u16* o = out + (size_t)orow * (3 * Kt) + coloff + kk;
    *(us8*)o = h; *(us8*)(o + Kt) = m; *(us8*)(o + 2 * Kt) = l;
}

// bias permute into gate-interleaved col space
__global__ __launch_bounds__(256)
void permute_bias_lstm(const float* __restrict__ b, float* __restrict__ out)
{
    const int c = blockIdx.x * 256 + threadIdx.x;
    const int jg = c >> 6, g = (c >> 4) & 3, jlo = c & 15;
    out[c] = b[g * 1024 + jg * 16 + jlo];
}

// Transpose + W-side split: W f32 [K][N] -> out u16 [N][3K].
__global__ __launch_bounds__(256)
void transpose_split3_w(const float* __restrict__ W, int N, int K,
                        u16* __restrict__ out)
{
    const int n0 = blockIdx.x * 64, k0 = blockIdx.y * 64;
    const int tid = threadIdx.x;
    __shared__ float ts[64][65];
    for (int i = 0; i < 16; ++i) {
        const int idx = i * 256 + tid;
        const int kl = idx >> 6, nl = idx & 63;
        float v = 0.f;
        if (n0 + nl < N) v = W[(size_t)(k0 + kl) * N + n0 + nl];
        ts[nl][kl] = v;
    }
    __syncthreads();
    for (int i = 0; i < 2; ++i) {
        const int idx = i * 256 + tid;
        const int nl = idx >> 3, kc = (idx & 7) * 8;
        if (n0 + nl < N) {
            us8 h, m, l;
#pragma unroll
            for (int j = 0; j < 8; ++j) {
                u16 a, b, c; split1<true>(ts[nl][kc + j], a, b, c);
                h[j] = a; m[j] = b; l[j] = c;
            }
            u16* o = out + (size_t)(n0 + nl) * (3 * K) + k0 + kc;
            *(us8*)o = h; *(us8*)(o + K) = m; *(us8*)(o + 2 * K) = l;
        }
    }
}

// embedding lookup + relu + A-side split -> A2 rows [T*B][3072], demb segment
// at coloff 512 of a Kt=1024 triple ([pool(0:512) | demb(512:1024)]).
__global__ __launch_bounds__(256)
void embed_relu3(const int* __restrict__ question, const float* __restrict__ emb,
                 u16* __restrict__ A2)
{
    const int idx = blockIdx.x * 256 + threadIdx.x;
    const int r = idx >> 6, kk = (idx & 63) * 8;
    const int t = r / B, b = r - t * B;
    const int tok = (t == 0) ? SOS : question[b * T + t - 1];
    const float* s = emb + (size_t)tok * DW + kk;
    const float4 x0 = *(const float4*)s, x1 = *(const float4*)(s + 4);
    float xs[8] = {x0.x, x0.y, x0.z, x0.w, x1.x, x1.y, x1.z, x1.w};
    us8 h, m, l;
#pragma unroll
    for (int j = 0; j < 8; ++j) {
        u16 a, b2, c; split1<false>(fmaxf(xs[j], 0.f), a, b2, c);
        h[j] = a; m[j] = b2; l[j] = c;
    }
    u16* o = A2 + (size_t)r * 3072 + 512 + kk;
    *(us8*)o = h; *(us8*)(o + 1024) = m; *(us8*)(o + 2048) = l;
}

// pool attention scores (f32 mW)
__global__ __launch_bounds__(256)
void attn_score(const float* __restrict__ q, int qld,
                const float* __restrict__ mW, const float* __restrict__ v,
                float* __restrict__ score, int Nn, int Hd)
{
    const int n = blockIdx.x, b = blockIdx.y;
    const float* qp = q + (size_t)b * qld;
    const float* mp = mW + ((size_t)b * Nn + n) * Hd;
    float s = 0.f;
    for (int h = threadIdx.x; h < Hd; h += 256)
        s += tanhf(qp[h] + mp[h]) * v[h];
    __shared__ float red[4];
    const int lane = threadIdx.x & 63, wv = threadIdx.x >> 6;
    for (int o = 32; o; o >>= 1) s += __shfl_down(s, o, 64);
    if (lane == 0) red[wv] = s;
    __syncthreads();
    if (threadIdx.x == 0) score[(size_t)b * Nn + n] = red[0] + red[1] + red[2] + red[3];
}

// pool ctx -> broadcast triple into A2 pool segment (coloff 0) for all T rows
__global__ __launch_bounds__(256)
void attn_ctx_pool(const float* __restrict__ score, const float* __restrict__ m,
                   u16* __restrict__ A2, int Nn)
{
    constexpr int D = 512;
    const int b = blockIdx.x;
    __shared__ float aw[128];
    __shared__ float red[8];
    const int tid = threadIdx.x, lane = tid & 63, wv = tid >> 6;
    float mx = -3.4e38f;
    for (int n = tid; n < Nn; n += 256) mx = fmaxf(mx, score[(size_t)b * Nn + n]);
    for (int o = 32; o; o >>= 1) mx = fmaxf(mx, __shfl_down(mx, o, 64));
    if (lane == 0) red[wv] = mx;
    __syncthreads();
    mx = fmaxf(fmaxf(red[0], red[1]), fmaxf(red[2], red[3]));
    float se = 0.f;
    for (int n = tid; n < Nn; n += 256) {
        float e = expf(score[(size_t)b * Nn + n] - mx);
        aw[n] = e; se += e;
    }
    for (int o = 32; o; o >>= 1) se += __shfl_down(se, o, 64);
    if (lane == 0) red[4 + wv] = se;
    __syncthreads();
    const float inv = 1.0f / (red[4] + red[5] + red[6] + red[7]);
    for (int d = tid; d < D; d += 256) {
        float s = 0.f;
        for (int n = 0; n < Nn; ++n) s += aw[n] * m[((size_t)b * Nn + n) * D + d];
        s *= inv;
        u16 b0, b1, b2; split1<false>(s, b0, b1, b2);
        for (int tt = 0; tt < T; ++tt) {
            u16* o = A2 + ((size_t)tt * B + b) * 3072 + d;
            o[0] = b0; o[1024] = b1; o[2048] = b2;
        }
    }
}

// Fused in-loop attention, 512 threads (8 waves); mW in f16
__global__ __launch_bounds__(512)
void attn_fused(const float* __restrict__ qbuf,
                const u16* __restrict__ img_mW, const u16* __restrict__ ppl_mW,
                const float* __restrict__ img_v, const float* __restrict__ ppl_v,
                const float* __restrict__ img_feats, const float* __restrict__ ppl_feats,
                u16* __restrict__ x3)
{
    const int b = blockIdx.x;
    const int tid = threadIdx.x, lane = tid & 63, wv = tid >> 6;
    __shared__ float qs[2048];
    __shared__ float vs[2048];
    __shared__ float aw[136];
    __shared__ float awn[136];

    for (int i = tid; i < 2048; i += 512) {
        qs[i] = qbuf[(size_t)b * 2048 + i];
        vs[i] = (i < 1024) ? img_v[i] : ppl_v[i - 1024];
    }
    __syncthreads();

    for (int n = wv; n < NI; n += 8) {
        const u16* mp = img_mW + ((size_t)b * NI + n) * 1024;
        float s = 0.f;
#pragma unroll
        for (int u = 0; u < 2; ++u) {
            const int h = (lane + 64 * u) * 8;
            const us8 m8 = *(const us8*)(mp + h);
#pragma unroll
            for (int j = 0; j < 8; ++j)
                s += tanhf(qs[h + j] + h2f(m8[j])) * vs[h + j];
        }
        for (int o = 1; o < 64; o <<= 1) s += __shfl_xor(s, o, 64);
        if (lane == 0) aw[n] = s;
    }
    for (int n = wv; n < NP; n += 8) {
        const u16* mp = ppl_mW + ((size_t)b * NP + n) * 1024;
        float s = 0.f;
#pragma unroll
        for (int u = 0; u < 2; ++u) {
            const int h = (lane + 64 * u) * 8;
            const us8 m8 = *(const us8*)(mp + h);
#pragma unroll
            for (int j = 0; j < 8; ++j)
                s += tanhf(qs[1024 + h + j] + h2f(m8[j])) * vs[1024 + h + j];
        }
        for (int o = 1; o < 64; o <<= 1) s += __shfl_xor(s, o, 64);
        if (lane == 0) aw[36 + n] = s;
    }
    __syncthreads();

    if (wv == 0) {
        const float x = (lane < NI) ? aw[lane] : -3.4e38f;
        float mx = x;
        for (int o = 1; o < 64; o <<= 1) mx = fmaxf(mx, __shfl_xor(mx, o, 64));
        const float e = (lane < NI) ? expf(x - mx) : 0.f;
        float ss = e;
        for (int o = 1; o < 64; o <<= 1) ss += __shfl_xor(ss, o, 64);
        if (lane < NI) awn[lane] = e / ss;
    } else if (wv == 1) {
        const float x0 = aw[36 + lane];
        const float x1 = (lane < NP - 64) ? aw[100 + lane] : -3.4e38f;
        float mx = fmaxf(x0, x1);
        for (int o = 1; o < 64; o <<= 1) mx = fmaxf(mx, __shfl_xor(mx, o, 64));
        const float e0 = expf(x0 - mx);
        const float e1 = (lane < NP - 64) ? expf(x1 - mx) : 0.f;
        float ss = e0 + e1;
        for (int o = 1; o < 64; o <<= 1) ss += __shfl_xor(ss, o, 64);
        awn[36 + lane] = e0 / ss;
        if (lane < NP - 64) awn[100 + lane] = e1 / ss;
    }
    __syncthreads();

    {
        const int d = tid;   // 512 threads == D
        float s = 0.f;
        const float* ip = img_feats + (size_t)b * NI * 512 + d;
#pragma unroll 4
        for (int n = 0; n < NI; ++n) s += awn[n] * ip[n * 512];
        const float* pp = ppl_feats + (size_t)b * NP * 512 + d;
#pragma unroll 4
        for (int n = 0; n < NP; ++n) s += awn[36 + n] * pp[n * 512];
        u16 b0, b1, b2; split1<false>(s, b0, b1, b2);
        u16* o = x3 + (size_t)b * 7680 + d;
        o[0] = b0; o[2560] = b1; o[5120] = b2;
    }
}

__global__ __launch_bounds__(256)
void zero_f(float* __restrict__ p) { p[blockIdx.x * 256 + threadIdx.x] = 0.f; }

__global__ __launch_bounds__(256)
void zero_u32(unsigned int* __restrict__ p) { p[blockIdx.x * 256 + threadIdx.x] = 0u; }

// online log_softmax over out rows [r][V], argmax -> out[BTV+r]
__global__ __launch_bounds__(256)
void logsm_argmax(float* __restrict__ out)
{
    const int r = blockIdx.x;
    float* row = out + (size_t)r * V;
    const int tid = threadIdx.x, lane = tid & 63, wv = tid >> 6;
    float m = -3.4e38f, s = 0.f; int mi = 0;
    for (int i4 = tid; i4 < V / 4; i4 += 256) {
        const float4 x4 = ((const float4*)row)[i4];
        const float xs[4] = {x4.x, x4.y, x4.z, x4.w};
#pragma unroll
        for (int j = 0; j < 4; ++j) {
            const float x = xs[j];
            if (x > m) { s = s * expf(m - x) + 1.f; m = x; mi = i4 * 4 + j; }
            else       s += expf(x - m);
        }
    }
    for (int o = 1; o < 64; o <<= 1) {
        const float m2 = __shfl_xor(m, o, 64);
        const float s2 = __shfl_xor(s, o, 64);
        const int  mi2 = __shfl_xor(mi, o, 64);
        if (m2 > m || (m2 == m && mi2 < mi)) { s = s2 + s * expf(m - m2); m = m2; mi = mi2; }
        else s += s2 * expf(m2 - m);
    }
    __shared__ float sm[4], ssm[4]; __shared__ int smi[4];
    __shared__ float lse_sh; __shared__ int mi_sh;
    if (lane == 0) { sm[wv] = m; ssm[wv] = s; smi[wv] = mi; }
    __syncthreads();
    if (tid == 0) {
        float M = sm[0], S = ssm[0]; int MI = smi[0];
        for (int w = 1; w < 4; ++w) {
            if (sm[w] > M || (sm[w] == M && smi[w] < MI)) { S = ssm[w] + S * expf(M - sm[w]); M = sm[w]; MI = smi[w]; }
            else S += ssm[w] * expf(sm[w] - M);
        }
        lse_sh = M + logf(S); mi_sh = MI;
    }
    __syncthreads();
    const float lse = lse_sh;
    for (int i4 = tid; i4 < V / 4; i4 += 256) {
        float4 x4 = ((const float4*)row)[i4];
        x4.x -= lse; x4.y -= lse; x4.z -= lse; x4.w -= lse;
        ((float4*)row)[i4] = x4;
    }
    if (tid == 0) out[(size_t)B * T * V + r] = (float)mi_sh;
}

// ---------------------------------------------------------------------------
extern "C" void kernel_launch(void* const* d_in, const int* in_sizes, int n_in,
                              void* d_out, int out_size, void* d_ws, size_t ws_size,
                              hipStream_t stream)
{
    (void)in_sizes; (void)n_in; (void)out_size; (void)ws_size;

    const float* img_feats   = (const float*)d_in[0];
    const float* ppl_feats   = (const float*)d_in[1];
    const float* answer_hint = (const float*)d_in[2];
    const int*   question    = (const int*)d_in[3];
    const float* emb         = (const float*)d_in[4];
    const float* pool_Wq     = (const float*)d_in[5];
    const float* pool_Wm     = (const float*)d_in[6];
    const float* pool_b      = (const float*)d_in[7];
    const float* pool_v      = (const float*)d_in[8];
    const float* img_Wq      = (const float*)d_in[9];
    const float* img_Wm      = (const float*)d_in[10];
    const float* img_b       = (const float*)d_in[11];
    const float* img_v       = (const float*)d_in[12];
    const float* ppl_Wq      = (const float*)d_in[13];
    const float* ppl_Wm      = (const float*)d_in[14];
    const float* ppl_b       = (const float*)d_in[15];
    const float* ppl_v       = (const float*)d_in[16];
    const float* vis_Wih     = (const float*)d_in[17];
    const float* vis_Whh     = (const float*)d_in[18];
    const float* vis_b       = (const float*)d_in[19];
    const float* lang_Wih    = (const float*)d_in[20];
    const float* lang_Whh    = (const float*)d_in[21];
    const float* lang_b      = (const float*)d_in[22];
    const float* proj_W      = (const float*)d_in[23];
    const float* proj_b      = (const float*)d_in[24];

    float* out = (float*)d_out;
    float* ws  = (float*)d_ws;

    size_t off = 0;
    auto alloc = [&](size_t nf) { size_t r = off; off += (nf + 63) & ~(size_t)63; return r; };
    // Region X: dead after the decode loop; projW3t overlaid post-loop.
    const size_t regionX = off;
    float* g_pre   = ws + alloc((size_t)T * B * G4);
    float* pool_mW = ws + alloc((size_t)B * NI * DW);
    u16*   A2      = (u16*)(ws + alloc((size_t)T * B * 3072 / 2));   // [pool|demb] triple
    u16*   hint3   = (u16*)(ws + alloc((size_t)B * 1536 / 2));
    u16*   poolWq3t= (u16*)(ws + alloc((size_t)512 * 1536 / 2));
    u16*   poolWm3t= (u16*)(ws + alloc((size_t)512 * 1536 / 2));
    u16*   visWih3 = (u16*)(ws + alloc((size_t)G4 * 3072 / 2));      // interleaved rows
    u16*   img_mW  = (u16*)(ws + alloc((size_t)B * NI * H / 2));     // f16, dead post-loop
    u16*   ppl_mW  = (u16*)(ws + alloc((size_t)B * NP * H / 2));     // f16, dead post-loop
    u16*   img3    = (u16*)(ws + alloc((size_t)B * NI * 1536 / 2));
    u16*   ppl3    = (u16*)(ws + alloc((size_t)B * NP * 1536 / 2));
    // persistent beyond overlay reach
    u16* visWhh3   = (u16*)(ws + alloc((size_t)G4 * 3072 / 2));
    u16* langW3    = (u16*)(ws + alloc((size_t)G4 * 7680 / 2));
    u16* wq3t      = (u16*)(ws + alloc((size_t)2048 * 3072 / 2));
    u16* imgWm3t   = (u16*)(ws + alloc((size_t)1024 * 1536 / 2));
    u16* pplWm3t   = (u16*)(ws + alloc((size_t)1024 * 1536 / 2));
    float* c_vis   = ws + alloc((size_t)B * H);
    float* c_lang  = ws + alloc((size_t)B * H);
    u16* a3        = (u16*)(ws + alloc((size_t)2 * B * 3072 / 2));   // dbuf, contiguous with x3
    u16* x3        = (u16*)(ws + alloc((size_t)2 * B * 7680 / 2));
    u16* h3_all    = (u16*)(ws + alloc((size_t)B * T * 3072 / 2));
    float* qbuf    = ws + alloc((size_t)B * 2048);
    float* vis_bi  = ws + alloc((size_t)G4);
    float* lang_bi = ws + alloc((size_t)G4);
    float* pool_qW = ws + alloc((size_t)B * DW);
    float* pool_sc = ws + alloc((size_t)B * NI);
    u16* projW3t   = (u16*)(ws + regionX);   // overlay over dead region

    const dim3 blk(256);

    // ---- init state ----
    zero_f<<<dim3((2 * B * H) / 256), blk, 0, stream>>>(c_vis);
    zero_u32<<<dim3((2 * B * 3072 + 2 * B * 7680) / 2 / 256), blk, 0, stream>>>((unsigned int*)a3);

    // ---- one-time splits / transposes ----
    embed_relu3<<<dim3(T * B * 64 / 256), blk, 0, stream>>>(question, emb, A2);
    permute_bias_lstm<<<dim3(16), blk, 0, stream>>>(vis_b, vis_bi);
    permute_bias_lstm<<<dim3(16), blk, 0, stream>>>(lang_b, lang_bi);
    split3_lstm<<<dim3(G4 * 128 / 256), blk, 0, stream>>>(vis_Wih, 1024, 128, visWih3, 1024, 0);
    split3_lstm<<<dim3(G4 * 128 / 256), blk, 0, stream>>>(vis_Whh, 1024, 128, visWhh3, 1024, 0);
    split3_lstm<<<dim3(G4 * 192 / 256), blk, 0, stream>>>(lang_Wih, 1536, 192, langW3, 2560, 0);
    split3_lstm<<<dim3(G4 * 128 / 256), blk, 0, stream>>>(lang_Whh, 1024, 128, langW3, 2560, 1536);
    split3_rows<false><<<dim3(B * NI * 64 / 256), blk, 0, stream>>>(img_feats, 512, 64, img3, 512, 0);
    split3_rows<false><<<dim3(B * NP * 64 / 256), blk, 0, stream>>>(ppl_feats, 512, 64, ppl3, 512, 0);
    split3_rows<false><<<dim3(B * 64 / 256), blk, 0, stream>>>(answer_hint, 512, 64, hint3, 512, 0);
    transpose_split3_w<<<dim3(8, 8), blk, 0, stream>>>(pool_Wq, 512, 512, poolWq3t);
    transpose_split3_w<<<dim3(8, 8), blk, 0, stream>>>(pool_Wm, 512, 512, poolWm3t);
    transpose_split3_w<<<dim3(16, 8), blk, 0, stream>>>(img_Wm, 1024, 512, imgWm3t);
    transpose_split3_w<<<dim3(16, 8), blk, 0, stream>>>(ppl_Wm, 1024, 512, pplWm3t);
    transpose_split3_w<<<dim3(16, 16), blk, 0, stream>>>(img_Wq, 1024, 1024, wq3t);
    transpose_split3_w<<<dim3(16, 16), blk, 0, stream>>>(ppl_Wq, 1024, 1024, wq3t + (size_t)1024 * 3072);

    // ---- precompute ----
    gemm3<64, 64, false, false><<<dim3(8, 2), blk, 0, stream>>>(hint3, poolWq3t, nullptr, nullptr, pool_qW, 512, 1536);
    gemm3<128, 128, false, true><<<dim3(4, 36), blk, 0, stream>>>(img3, poolWm3t, nullptr, pool_b, pool_mW, 512, 1536);
    attn_score<<<dim3(NI, B), blk, 0, stream>>>(pool_qW, 512, pool_mW, pool_v, pool_sc, NI, 512);
    attn_ctx_pool<<<dim3(B), blk, 0, stream>>>(pool_sc, img_feats, A2, NI);
    // g_pre = A2 @ visWih3^T + vis_b  (single fused GEMM, K3=3072)
    gemm3<128, 128, false, true><<<dim3(32, 20), blk, 0, stream>>>(A2, visWih3, nullptr, vis_bi, g_pre, G4, 3072);
    // attention memories -> f16 (+bias folded)
    gemm3<128, 128, false, true, 0, true><<<dim3(8, 36), blk, 0, stream>>>(img3, imgWm3t, nullptr, img_b, img_mW, H, 1536);
    gemm3<128, 128, false, true, 0, true><<<dim3(8, 100), blk, 0, stream>>>(ppl3, pplWm3t, nullptr, ppl_b, ppl_mW, H, 1536);

    // ---- sequential decode: combo[lang(t-1) || vis(t)] -> q(t) -> attn(t) ----
    for (int t = 0; t <= T; ++t) {
        u16* lang_A  = x3 + (size_t)((t + 1) & 1) * B * 7680;   // x3(t-1)
        u16* lang_o1 = x3 + (size_t)(t & 1) * B * 7680;         // x3(t)
        u16* vis_A   = a3 + (size_t)(t & 1) * B * 3072;         // h_vis(t-1) triple
        u16* vis_o1  = a3 + (size_t)((t + 1) & 1) * B * 3072;   // h_vis(t) triple
        u16* vis_o2  = x3 + (size_t)(t & 1) * B * 7680;         // x3(t)
        const float* gp = g_pre + (size_t)(t < T ? t : 0) * B * G4;
        step_combo<<<dim3(64, 2, 2), blk, 0, stream>>>(
            lang_A, langW3, lang_bi, c_lang, lang_o1, h3_all,
            vis_A, visWhh3, gp, c_vis, vis_o1, vis_o2, t);
        if (t < T) {
            gemm_q<<<dim3(128, 2), blk, 0, stream>>>(vis_o1, wq3t, qbuf, 2048, 3072);
            attn_fused<<<dim3(B), dim3(512), 0, stream>>>(qbuf, img_mW, ppl_mW, img_v, ppl_v,
                                                          img_feats, ppl_feats, vis_o2);
        }
    }

    // ---- deferred projection (super-tiled for L3 reuse) ----
    transpose_split3_w<<<dim3(313, 16), blk, 0, stream>>>(proj_W, V, 1024, projW3t);
    gemm3<128, 128, false, true, 20><<<dim3(157, 20), blk, 0, stream>>>(
        h3_all, projW3t, nullptr, proj_b, out, V, 3072);
    logsm_argmax<<<dim3(B * T), blk, 0, stream>>>(out);
}

// Round 12
// 3419.214 us; speedup vs baseline: 1.2095x; 1.0468x over previous
//
#include <hip/hip_runtime.h>
#include <cstddef>
#include <cstdint>

using u16 = unsigned short;
typedef float    f32x4 __attribute__((ext_vector_type(4)));
typedef _Float16 f16x8 __attribute__((ext_vector_type(8)));
typedef u16      us8   __attribute__((ext_vector_type(8)));

constexpr int B  = 128;
constexpr int T  = 20;
constexpr int V  = 20000;
constexpr int DW = 512;
constexpr int H  = 1024;
constexpr int G4 = 4096;
constexpr int NI = 36;
constexpr int NP = 100;
constexpr int SOS = 1;

__device__ __forceinline__ float sigf(float x) { return 1.0f / (1.0f + expf(-x)); }
__device__ __forceinline__ u16 f16bits(_Float16 h) { u16 u; __builtin_memcpy(&u, &h, 2); return u; }
__device__ __forceinline__ float h2f(u16 u) { _Float16 h; __builtin_memcpy(&h, &u, 2); return (float)h; }

// f16x3 split: x ~= hi + lo as triples; one K-expanded f16 GEMM computes
// hi*hi + lo*hi + hi*lo (error ~2^-22). A: [hi, lo*64, hi/64]; W: [hi, hi/64, lo*64]
template<bool WSIDE>
__device__ __forceinline__ void split1(float x, u16& b0, u16& b1, u16& b2) {
    _Float16 h  = (_Float16)x;
    float    hf = (float)h;
    _Float16 lo = (_Float16)((x - hf) * 64.0f);
    _Float16 hs = (_Float16)(hf * (1.0f / 64.0f));
    b0 = f16bits(h);
    if constexpr (WSIDE) { b1 = f16bits(hs); b2 = f16bits(lo); }
    else                 { b1 = f16bits(lo); b2 = f16bits(hs); }
}

// ---------------------------------------------------------------------------
// Generic MFMA GEMM (precompute + proj): C[M,N] = A3[M,K3] x B3t[N,K3]^T.
// BK=64, 4 waves 2x2, software-pipelined. NSW>0: super-tile remap for L3 reuse.
// OUTF16: write C as f16.
// ---------------------------------------------------------------------------
template<int BM, int BN, bool HAS_ADD, bool HAS_BIAS, int NSW = 0, bool OUTF16 = false>
__global__ __launch_bounds__(256)
void gemm3(const u16* __restrict__ A, const u16* __restrict__ Bt,
           const float* __restrict__ Add, const float* __restrict__ bias,
           void* __restrict__ Cv, int N, int K3)
{
    __shared__ __align__(16) u16 As[BM * 64];
    __shared__ __align__(16) u16 Bs[BN * 64];
    constexpr int FR = BM / 32, FC = BN / 32, PA = BM / 32, PB = BN / 32;
    const int tid  = threadIdx.x;
    int bx = blockIdx.x, by = blockIdx.y;
    if constexpr (NSW > 0) {
        const int nt = (int)gridDim.x, mt = (int)gridDim.y;
        const int lin = by * nt + bx;
        const int sc0 = (lin / (NSW * mt)) * NSW;
        const int w   = (NSW < nt - sc0) ? NSW : (nt - sc0);
        const int r   = lin - sc0 * mt;
        bx = sc0 + r % w;
        by = r / w;
    }
    const int bm   = by * BM, bn = bx * BN;
    const int lane = tid & 63, wid = tid >> 6;
    const int wm   = (wid >> 1) * (BM / 2), wn = (wid & 1) * (BN / 2);
    const int srow = tid >> 3;
    const int scol = (tid & 7) * 8;

    f32x4 acc[FR][FC] = {};
    us8 ra[PA], rb[PB];

    auto ldg = [&](int k0) {
#pragma unroll
        for (int p = 0; p < PA; ++p)
            ra[p] = *(const us8*)(A + (size_t)(bm + p * 32 + srow) * K3 + k0 + scol);
#pragma unroll
        for (int p = 0; p < PB; ++p) {
            int n = bn + p * 32 + srow; if (n > N - 1) n = N - 1;
            rb[p] = *(const us8*)(Bt + (size_t)n * K3 + k0 + scol);
        }
    };
    ldg(0);

    for (int k0 = 0; k0 < K3; k0 += 64) {
        __syncthreads();
#pragma unroll
        for (int p = 0; p < PA; ++p) {
            const int row = p * 32 + srow;
            *(us8*)((char*)As + row * 128 + ((scol * 2) ^ ((row & 7) << 4))) = ra[p];
        }
#pragma unroll
        for (int p = 0; p < PB; ++p) {
            const int row = p * 32 + srow;
            *(us8*)((char*)Bs + row * 128 + ((scol * 2) ^ ((row & 7) << 4))) = rb[p];
        }
        __syncthreads();
        if (k0 + 64 < K3) ldg(k0 + 64);
#pragma unroll
        for (int ks = 0; ks < 2; ++ks) {
            f16x8 af[FR], bf[FC];
#pragma unroll
            for (int m = 0; m < FR; ++m) {
                const int row = wm + m * 16 + (lane & 15);
                const int cb  = (ks * 64 + ((lane >> 4) << 4)) ^ ((row & 7) << 4);
                af[m] = *(const f16x8*)((const char*)As + row * 128 + cb);
            }
#pragma unroll
            for (int n = 0; n < FC; ++n) {
                const int row = wn + n * 16 + (lane & 15);
                const int cb  = (ks * 64 + ((lane >> 4) << 4)) ^ ((row & 7) << 4);
                bf[n] = *(const f16x8*)((const char*)Bs + row * 128 + cb);
            }
#pragma unroll
            for (int m = 0; m < FR; ++m)
#pragma unroll
                for (int n = 0; n < FC; ++n)
                    acc[m][n] = __builtin_amdgcn_mfma_f32_16x16x32_f16(af[m], bf[n], acc[m][n], 0, 0, 0);
        }
    }
#pragma unroll
    for (int m = 0; m < FR; ++m) {
        const int r0 = bm + wm + m * 16 + ((lane >> 4) << 2);
#pragma unroll
        for (int n = 0; n < FC; ++n) {
            const int c = bn + wn + n * 16 + (lane & 15);
            if (c < N) {
#pragma unroll
                for (int j = 0; j < 4; ++j) {
                    float v = acc[m][n][j];
                    if constexpr (HAS_ADD)  v += Add[(size_t)(r0 + j) * N + c];
                    if constexpr (HAS_BIAS) v += bias[c];
                    if constexpr (OUTF16)
                        ((u16*)Cv)[(size_t)(r0 + j) * N + c] = f16bits((_Float16)v);
                    else
                        ((float*)Cv)[(size_t)(r0 + j) * N + c] = v;
                }
            }
        }
    }
}

// ---------------------------------------------------------------------------
// In-loop GEMM core (BM=64, BN/BK params), 256 threads, 4 waves each 16 rows x
// BN cols. EPI=0: plain f32 C. EPI=1: vis-LSTM (+Add=g_pre). EPI=2: lang-LSTM
// (+Add=gates_hh). EPI=3: plain f32 C + bias (interleaved col space).
// ---------------------------------------------------------------------------
template<int EPI, int BN, int BK>
__device__ __forceinline__ void gemm_core(
    u16* As, u16* Bs,
    const u16* A, const u16* Bt,
    const float* Add, const float* bias,
    float* CS, u16* o1, u16* o2,
    int N, int K3, int t, int bx, int by)
{
    constexpr int NA8  = BK / 32;
    constexpr int TPRB = 256 / BN;
    constexpr int NB8  = (BK / TPRB) / 8;
    constexpr int NFC  = BN / 16;
    const int tid  = threadIdx.x;
    const int bn   = bx * BN, bm = by * 64;
    const int lane = tid & 63, wv = tid >> 6;
    const int rowA = tid >> 2;
    const int scA  = (tid & 3) * (BK / 4);
    const int rowB = tid / TPRB;
    const int scB  = (tid % TPRB) * (BK / TPRB);
    const int swzA = (rowA & 7) << 4;
    const int swzB = (rowB & 7) << 4;
    const u16* Ap = A  + (size_t)(bm + rowA) * K3 + scA;
    const u16* Bp = Bt + (size_t)(bn + rowB) * K3 + scB;
    char* Awp = (char*)As + rowA * (BK * 2);
    char* Bwp = (char*)Bs + rowB * (BK * 2);
    const int arow = wv * 16 + (lane & 15);
    const char* Arp = (const char*)As + arow * (BK * 2);
    const int aswz = (arow & 7) << 4;
    const int jl   = lane & 15;

    f32x4 acc[NFC] = {};
    us8 ra[NA8], rb[NB8];
#pragma unroll
    for (int i = 0; i < NA8; ++i) ra[i] = *(const us8*)(Ap + 8 * i);
#pragma unroll
    for (int i = 0; i < NB8; ++i) rb[i] = *(const us8*)(Bp + 8 * i);

    for (int k0 = 0; k0 < K3; k0 += BK) {
        __syncthreads();
#pragma unroll
        for (int i = 0; i < NA8; ++i)
            *(us8*)(Awp + ((scA * 2 + 16 * i) ^ swzA)) = ra[i];
#pragma unroll
        for (int i = 0; i < NB8; ++i)
            *(us8*)(Bwp + ((scB * 2 + 16 * i) ^ swzB)) = rb[i];
        __syncthreads();
        if (k0 + BK < K3) {
#pragma unroll
            for (int i = 0; i < NA8; ++i) ra[i] = *(const us8*)(Ap + k0 + BK + 8 * i);
#pragma unroll
            for (int i = 0; i < NB8; ++i) rb[i] = *(const us8*)(Bp + k0 + BK + 8 * i);
        }
#pragma unroll
        for (int ks = 0; ks < BK / 32; ++ks) {
            const int cb = ks * 64 + ((lane >> 4) << 4);
            const f16x8 af = *(const f16x8*)(Arp + (cb ^ aswz));
#pragma unroll
            for (int g = 0; g < NFC; ++g) {
                const int brow = g * 16 + jl;
                const f16x8 bf = *(const f16x8*)((const char*)Bs + brow * (BK * 2) + (cb ^ ((brow & 7) << 4)));
                acc[g] = __builtin_amdgcn_mfma_f32_16x16x32_f16(af, bf, acc[g], 0, 0, 0);
            }
        }
    }
    const int rb0 = bm + wv * 16 + ((lane >> 4) << 2);
    if constexpr (EPI == 0 || EPI == 3) {
#pragma unroll
        for (int g = 0; g < NFC; ++g) {
            const int c = bn + g * 16 + jl;
#pragma unroll
            for (int jj = 0; jj < 4; ++jj) {
                float v = acc[g][jj];
                if constexpr (EPI == 3) v += bias[c];
                CS[(size_t)(rb0 + jj) * N + c] = v;
            }
        }
    } else {
        const int j = bx * 16 + jl;
#pragma unroll
        for (int jj = 0; jj < 4; ++jj) {
            const int b = rb0 + jj;
            float gi = acc[0][jj], gf = acc[1][jj], gg = acc[2][jj], go = acc[3][jj];
            {
                const float* ap = Add + (size_t)b * 4096 + bn + jl;
                gi += ap[0]; gf += ap[16]; gg += ap[32]; go += ap[48];
            }
            const float c = sigf(gf) * CS[b * 1024 + j] + sigf(gi) * tanhf(gg);
            const float h = sigf(go) * tanhf(c);
            CS[b * 1024 + j] = c;
            u16 b0, b1, b2; split1<false>(h, b0, b1, b2);
            if constexpr (EPI == 1) {
                u16* a = o1 + (size_t)b * 3072 + j;           // a3: h_vis triple
                a[0] = b0; a[1024] = b1; a[2048] = b2;
                u16* x = o2 + (size_t)b * 4608 + 512 + j;     // x4 h_vis slot (Kt=1536)
                x[0] = b0; x[1536] = b1; x[3072] = b2;
            } else {                                          // EPI == 2
                u16* hl = o1 + (size_t)b * 3072 + j;          // hl3: h_lang triple
                hl[0] = b0; hl[1024] = b1; hl[2048] = b2;
                u16* hh = o2 + ((size_t)b * T + t) * 3072 + j; // h3_all
                hh[0] = b0; hh[1024] = b1; hh[2048] = b2;
            }
        }
    }
}

// q + lang-hh fused launch: blocks [0,256) q(t) (BN=16), [256,512) hh (BN=32).
// hh: gates_hh = hl3(t-1) @ langWhh3^T + lang_bi (interleaved cols).
__global__ __launch_bounds__(256)
void gemm_q_hh(const u16* __restrict__ a3_new, const u16* __restrict__ wq3t,
               float* qbuf,
               const u16* __restrict__ hl_prev, const u16* __restrict__ langWhh3,
               const float* __restrict__ lang_bi, float* gates_hh)
{
    __shared__ __align__(16) u16 As[64 * 384];
    __shared__ __align__(16) u16 Bs[32 * 384];
    const int blk = blockIdx.x;
    if (blk < 256) {
        gemm_core<0, 16, 384>(As, Bs, a3_new, wq3t, nullptr, nullptr,
                              qbuf, nullptr, nullptr, 2048, 3072, 0,
                              blk & 127, blk >> 7);
    } else {
        const int b2 = blk - 256;
        gemm_core<3, 32, 384>(As, Bs, hl_prev, langWhh3, nullptr, lang_bi,
                              gates_hh, nullptr, nullptr, 4096, 3072, 0,
                              b2 & 127, b2 >> 7);
    }
}

// Combined step kernel: z=0 -> lang(t-1) K=4608 (skip t==0), z=1 -> vis(t)
// (skip t==T). grid (64,2,2), 256 threads, BK=384 (96 KB LDS).
__global__ __launch_bounds__(256)
void step_combo(const u16* __restrict__ lang_A, const u16* __restrict__ langWih3,
                const float* __restrict__ gates_hh, float* c_lang,
                u16* hl_out, u16* h3_all,
                const u16* __restrict__ vis_A, const u16* __restrict__ visWhh3,
                const float* __restrict__ g_pre_t, float* c_vis,
                u16* vis_o1, u16* vis_o2, int t)
{
    __shared__ __align__(16) u16 As[64 * 384];
    __shared__ __align__(16) u16 Bs[64 * 384];
    if (blockIdx.z == 0) {
        if (t >= 1)
            gemm_core<2, 64, 384>(As, Bs, lang_A, langWih3, gates_hh, nullptr,
                                  c_lang, hl_out, h3_all, G4, 4608, t - 1,
                                  blockIdx.x, blockIdx.y);
    } else {
        if (t < T)
            gemm_core<1, 64, 384>(As, Bs, vis_A, visWhh3, g_pre_t, nullptr,
                                  c_vis, vis_o1, vis_o2, G4, 3072, t,
                                  blockIdx.x, blockIdx.y);
    }
}

// ---------------------------------------------------------------------------
// Row-major split: src f32 [M][ld] -> triple cols in out [M][3*Kt].
template<bool WSIDE>
__global__ __launch_bounds__(256)
void split3_rows(const float* __restrict__ src, int ld, int K8,
                 u16* __restrict__ out, int Kt, int coloff)
{
    const int idx = blockIdx.x * 256 + threadIdx.x;
    const int r = idx / K8, kk = (idx - r * K8) * 8;
    const float* s = src + (size_t)r * ld + kk;
    const float4 x0 = *(const float4*)s, x1 = *(const float4*)(s + 4);
    float xs[8] = {x0.x, x0.y, x0.z, x0.w, x1.x, x1.y, x1.z, x1.w};
    us8 h, m, l;
#pragma unroll
    for (int j = 0; j < 8; ++j) { u16 a, b, c; split1<WSIDE>(xs[j], a, b, c); h[j]=a; m[j]=b; l[j]=c; }
    u16* o = out + (size_t)r * (3 * Kt) + coloff + kk;
    *(us8*)o = h; *(us8*)(o + Kt) = m; *(us8*)(o + 2 * Kt) = l;
}

// LSTM weight split, gate-interleaved output rows: src row r = g*1024+j ->
// out row (j>>4)*64 + g*16 + (j&15). W-side triple.
__global__ __launch_bounds__(256)
void split3_lstm(const float* __restrict__ src, int ld, int K8,
                 u16* __restrict__ out, int Kt, int coloff)
{
    const int idx = blockIdx.x * 256 + threadIdx.x;
    const int r = idx / K8, kk = (idx - r * K8) * 8;
    const int g = r >> 10, j = r & 1023;
    const int orow = ((j >> 4) << 6) + (g << 4) + (j & 15);
    const float* s = src + (size_t)r * ld + kk;
    const float4 x0 = *(const float4*)s, x1 = *(const float4*)(s + 4);
    float xs[8] = {x0.x, x0.y, x0.z, x0.w, x1.x, x1.y, x1.z, x1.w};
    us8 h, m, l;
#pragma unroll
    for (int jj = 0; jj < 8; ++jj) { u16 a, b, c; split1<true>(xs[jj], a, b, c); h[jj]=a; m[jj]=b; l[jj]=c; }
    u16* o = out + (size_t)orow * (3 * Kt) + coloff + kk;
    *(us8*)o = h; *(us8*)(o + Kt) = m; *(us8*)(o + 2 * Kt) = l;
}

// bias permute into gate-interleaved col space
__global__ __launch_bounds__(256)
void permute_bias_lstm(const float* __restrict__ b, float* __restrict__ out)
{
    const int c = blockIdx.x * 256 + threadIdx.x;
    const int jg = c >> 6, g = (c >> 4) & 3, jlo = c & 15;
    out[c] = b[g * 1024 + jg * 16 + jlo];
}

// Transpose + W-side split: W f32 [K][N] -> out u16 [N][3K].
__global__ __launch_bounds__(256)
void transpose_split3_w(const float* __restrict__ W, int N, int K,
                        u16* __restrict__ out)
{
    const int n0 = blockIdx.x * 64, k0 = blockIdx.y * 64;
    const int tid = threadIdx.x;
    __shared__ float ts[64][65];
    for (int i = 0; i < 16; ++i) {
        const int idx = i * 256 + tid;
        const int kl = idx >> 6, nl = idx & 63;
        float v = 0.f;
        if (n0 + nl < N) v = W[(size_t)(k0 + kl) * N + n0 + nl];
        ts[nl][kl] = v;
    }
    __syncthreads();
    for (int i = 0; i < 2; ++i) {
        const int idx = i * 256 + tid;
        const int nl = idx >> 3, kc = (idx & 7) * 8;
        if (n0 + nl < N) {
            us8 h, m, l;
#pragma unroll
            for (int j = 0; j < 8; ++j) {
                u16 a, b, c; split1<true>(ts[nl][kc + j], a, b, c);
                h[j] = a; m[j] = b; l[j] = c;
            }
            u16* o = out + (size_t)(n0 + nl) * (3 * K) + k0 + kc;
            *(us8*)o = h; *(us8*)(o + K) = m; *(us8*)(o + 2 * K) = l;
        }
    }
}

// embedding lookup + relu + A-side split -> A2 rows [T*B][3072], demb segment
// at coloff 512 of a Kt=1024 triple ([pool(0:512) | demb(512:1024)]).
__global__ __launch_bounds__(256)
void embed_relu3(const int* __restrict__ question, const float* __restrict__ emb,
                 u16* __restrict__ A2)
{
    const int idx = blockIdx.x * 256 + threadIdx.x;
    const int r = idx >> 6, kk = (idx & 63) * 8;
    const int t = r / B, b = r - t * B;
    const int tok = (t == 0) ? SOS : question[b * T + t - 1];
    const float* s = emb + (size_t)tok * DW + kk;
    const float4 x0 = *(const float4*)s, x1 = *(const float4*)(s + 4);
    float xs[8] = {x0.x, x0.y, x0.z, x0.w, x1.x, x1.y, x1.z, x1.w};
    us8 h, m, l;
#pragma unroll
    for (int j = 0; j < 8; ++j) {
        u16 a, b2, c; split1<false>(fmaxf(xs[j], 0.f), a, b2, c);
        h[j] = a; m[j] = b2; l[j] = c;
    }
    u16* o = A2 + (size_t)r * 3072 + 512 + kk;
    *(us8*)o = h; *(us8*)(o + 1024) = m; *(us8*)(o + 2048) = l;
}

// pool attention scores (f32 mW)
__global__ __launch_bounds__(256)
void attn_score(const float* __restrict__ q, int qld,
                const float* __restrict__ mW, const float* __restrict__ v,
                float* __restrict__ score, int Nn, int Hd)
{
    const int n = blockIdx.x, b = blockIdx.y;
    const float* qp = q + (size_t)b * qld;
    const float* mp = mW + ((size_t)b * Nn + n) * Hd;
    float s = 0.f;
    for (int h = threadIdx.x; h < Hd; h += 256)
        s += tanhf(qp[h] + mp[h]) * v[h];
    __shared__ float red[4];
    const int lane = threadIdx.x & 63, wv = threadIdx.x >> 6;
    for (int o = 32; o; o >>= 1) s += __shfl_down(s, o, 64);
    if (lane == 0) red[wv] = s;
    __syncthreads();
    if (threadIdx.x == 0) score[(size_t)b * Nn + n] = red[0] + red[1] + red[2] + red[3];
}

// pool ctx -> broadcast triple into A2 pool segment (coloff 0) for all T rows
__global__ __launch_bounds__(256)
void attn_ctx_pool(const float* __restrict__ score, const float* __restrict__ m,
                   u16* __restrict__ A2, int Nn)
{
    constexpr int D = 512;
    const int b = blockIdx.x;
    __shared__ float aw[128];
    __shared__ float red[8];
    const int tid = threadIdx.x, lane = tid & 63, wv = tid >> 6;
    float mx = -3.4e38f;
    for (int n = tid; n < Nn; n += 256) mx = fmaxf(mx, score[(size_t)b * Nn + n]);
    for (int o = 32; o; o >>= 1) mx = fmaxf(mx, __shfl_down(mx, o, 64));
    if (lane == 0) red[wv] = mx;
    __syncthreads();
    mx = fmaxf(fmaxf(red[0], red[1]), fmaxf(red[2], red[3]));
    float se = 0.f;
    for (int n = tid; n < Nn; n += 256) {
        float e = expf(score[(size_t)b * Nn + n] - mx);
        aw[n] = e; se += e;
    }
    for (int o = 32; o; o >>= 1) se += __shfl_down(se, o, 64);
    if (lane == 0) red[4 + wv] = se;
    __syncthreads();
    const float inv = 1.0f / (red[4] + red[5] + red[6] + red[7]);
    for (int d = tid; d < D; d += 256) {
        float s = 0.f;
        for (int n = 0; n < Nn; ++n) s += aw[n] * m[((size_t)b * Nn + n) * D + d];
        s *= inv;
        u16 b0, b1, b2; split1<false>(s, b0, b1, b2);
        for (int tt = 0; tt < T; ++tt) {
            u16* o = A2 + ((size_t)tt * B + b) * 3072 + d;
            o[0] = b0; o[1024] = b1; o[2048] = b2;
        }
    }
}

// Fused in-loop attention, 512 threads (8 waves); mW in f16, feats in f32.
// Writes x4 attn slot (Kt=1536).
__global__ __launch_bounds__(512)
void attn_fused(const float* __restrict__ qbuf,
                const u16* __restrict__ img_mW, const u16* __restrict__ ppl_mW,
                const float* __restrict__ img_v, const float* __restrict__ ppl_v,
                const float* __restrict__ img_feats, const float* __restrict__ ppl_feats,
                u16* __restrict__ x4)
{
    const int b = blockIdx.x;
    const int tid = threadIdx.x, lane = tid & 63, wv = tid >> 6;
    __shared__ float qs[2048];
    __shared__ float vs[2048];
    __shared__ float aw[136];
    __shared__ float awn[136];

    for (int i = tid; i < 2048; i += 512) {
        qs[i] = qbuf[(size_t)b * 2048 + i];
        vs[i] = (i < 1024) ? img_v[i] : ppl_v[i - 1024];
    }
    __syncthreads();

    for (int n = wv; n < NI; n += 8) {
        const u16* mp = img_mW + ((size_t)b * NI + n) * 1024;
        float s = 0.f;
#pragma unroll
        for (int u = 0; u < 2; ++u) {
            const int h = (lane + 64 * u) * 8;
            const us8 m8 = *(const us8*)(mp + h);
#pragma unroll
            for (int j = 0; j < 8; ++j)
                s += tanhf(qs[h + j] + h2f(m8[j])) * vs[h + j];
        }
        for (int o = 1; o < 64; o <<= 1) s += __shfl_xor(s, o, 64);
        if (lane == 0) aw[n] = s;
    }
    for (int n = wv; n < NP; n += 8) {
        const u16* mp = ppl_mW + ((size_t)b * NP + n) * 1024;
        float s = 0.f;
#pragma unroll
        for (int u = 0; u < 2; ++u) {
            const int h = (lane + 64 * u) * 8;
            const us8 m8 = *(const us8*)(mp + h);
#pragma unroll
            for (int j = 0; j < 8; ++j)
                s += tanhf(qs[1024 + h + j] + h2f(m8[j])) * vs[1024 + h + j];
        }
        for (int o = 1; o < 64; o <<= 1) s += __shfl_xor(s, o, 64);
        if (lane == 0) aw[36 + n] = s;
    }
    __syncthreads();

    if (wv == 0) {
        const float x = (lane < NI) ? aw[lane] : -3.4e38f;
        float mx = x;
        for (int o = 1; o < 64; o <<= 1) mx = fmaxf(mx, __shfl_xor(mx, o, 64));
        const float e = (lane < NI) ? expf(x - mx) : 0.f;
        float ss = e;
        for (int o = 1; o < 64; o <<= 1) ss += __shfl_xor(ss, o, 64);
        if (lane < NI) awn[lane] = e / ss;
    } else if (wv == 1) {
        const float x0 = aw[36 + lane];
        const float x1 = (lane < NP - 64) ? aw[100 + lane] : -3.4e38f;
        float mx = fmaxf(x0, x1);
        for (int o = 1; o < 64; o <<= 1) mx = fmaxf(mx, __shfl_xor(mx, o, 64));
        const float e0 = expf(x0 - mx);
        const float e1 = (lane < NP - 64) ? expf(x1 - mx) : 0.f;
        float ss = e0 + e1;
        for (int o = 1; o < 64; o <<= 1) ss += __shfl_xor(ss, o, 64);
        awn[36 + lane] = e0 / ss;
        if (lane < NP - 64) awn[100 + lane] = e1 / ss;
    }
    __syncthreads();

    {
        const int d = tid;   // 512 threads == D
        float s = 0.f;
        const float* ip = img_feats + (size_t)b * NI * 512 + d;
#pragma unroll 4
        for (int n = 0; n < NI; ++n) s += awn[n] * ip[n * 512];
        const float* pp = ppl_feats + (size_t)b * NP * 512 + d;
#pragma unroll 4
        for (int n = 0; n < NP; ++n) s += awn[36 + n] * pp[n * 512];
        u16 b0, b1, b2; split1<false>(s, b0, b1, b2);
        u16* o = x4 + (size_t)b * 4608 + d;
        o[0] = b0; o[1536] = b1; o[3072] = b2;
    }
}

__global__ __launch_bounds__(256)
void zero_f(float* __restrict__ p) { p[blockIdx.x * 256 + threadIdx.x] = 0.f; }

__global__ __launch_bounds__(256)
void zero_u32(unsigned int* __restrict__ p) { p[blockIdx.x * 256 + threadIdx.x] = 0u; }

// online log_softmax over out rows [r][V], argmax -> out[BTV+r]
__global__ __launch_bounds__(256)
void logsm_argmax(float* __restrict__ out)
{
    const int r = blockIdx.x;
    float* row = out + (size_t)r * V;
    const int tid = threadIdx.x, lane = tid & 63, wv = tid >> 6;
    float m = -3.4e38f, s = 0.f; int mi = 0;
    for (int i4 = tid; i4 < V / 4; i4 += 256) {
        const float4 x4 = ((const float4*)row)[i4];
        const float xs[4] = {x4.x, x4.y, x4.z, x4.w};
#pragma unroll
        for (int j = 0; j < 4; ++j) {
            const float x = xs[j];
            if (x > m) { s = s * expf(m - x) + 1.f; m = x; mi = i4 * 4 + j; }
            else       s += expf(x - m);
        }
    }
    for (int o = 1; o < 64; o <<= 1) {
        const float m2 = __shfl_xor(m, o, 64);
        const float s2 = __shfl_xor(s, o, 64);
        const int  mi2 = __shfl_xor(mi, o, 64);
        if (m2 > m || (m2 == m && mi2 < mi)) { s = s2 + s * expf(m - m2); m = m2; mi = mi2; }
        else s += s2 * expf(m2 - m);
    }
    __shared__ float sm[4], ssm[4]; __shared__ int smi[4];
    __shared__ float lse_sh; __shared__ int mi_sh;
    if (lane == 0) { sm[wv] = m; ssm[wv] = s; smi[wv] = mi; }
    __syncthreads();
    if (tid == 0) {
        float M = sm[0], S = ssm[0]; int MI = smi[0];
        for (int w = 1; w < 4; ++w) {
            if (sm[w] > M || (sm[w] == M && smi[w] < MI)) { S = ssm[w] + S * expf(M - sm[w]); M = sm[w]; MI = smi[w]; }
            else S += ssm[w] * expf(sm[w] - M);
        }
        lse_sh = M + logf(S); mi_sh = MI;
    }
    __syncthreads();
    const float lse = lse_sh;
    for (int i4 = tid; i4 < V / 4; i4 += 256) {
        float4 x4 = ((const float4*)row)[i4];
        x4.x -= lse; x4.y -= lse; x4.z -= lse; x4.w -= lse;
        ((float4*)row)[i4] = x4;
    }
    if (tid == 0) out[(size_t)B * T * V + r] = (float)mi_sh;
}

// ---------------------------------------------------------------------------
extern "C" void kernel_launch(void* const* d_in, const int* in_sizes, int n_in,
                              void* d_out, int out_size, void* d_ws, size_t ws_size,
                              hipStream_t stream)
{
    (void)in_sizes; (void)n_in; (void)out_size; (void)ws_size;

    const float* img_feats   = (const float*)d_in[0];
    const float* ppl_feats   = (const float*)d_in[1];
    const float* answer_hint = (const float*)d_in[2];
    const int*   question    = (const int*)d_in[3];
    const float* emb         = (const float*)d_in[4];
    const float* pool_Wq     = (const float*)d_in[5];
    const float* pool_Wm     = (const float*)d_in[6];
    const float* pool_b      = (const float*)d_in[7];
    const float* pool_v      = (const float*)d_in[8];
    const float* img_Wq      = (const float*)d_in[9];
    const float* img_Wm      = (const float*)d_in[10];
    const float* img_b       = (const float*)d_in[11];
    const float* img_v       = (const float*)d_in[12];
    const float* ppl_Wq      = (const float*)d_in[13];
    const float* ppl_Wm      = (const float*)d_in[14];
    const float* ppl_b       = (const float*)d_in[15];
    const float* ppl_v       = (const float*)d_in[16];
    const float* vis_Wih     = (const float*)d_in[17];
    const float* vis_Whh     = (const float*)d_in[18];
    const float* vis_b       = (const float*)d_in[19];
    const float* lang_Wih    = (const float*)d_in[20];
    const float* lang_Whh    = (const float*)d_in[21];
    const float* lang_b      = (const float*)d_in[22];
    const float* proj_W      = (const float*)d_in[23];
    const float* proj_b      = (const float*)d_in[24];

    float* out = (float*)d_out;
    float* ws  = (float*)d_ws;

    size_t off = 0;
    auto alloc = [&](size_t nf) { size_t r = off; off += (nf + 63) & ~(size_t)63; return r; };
    // Region X: dead after the decode loop; projW3t overlaid post-loop.
    const size_t regionX = off;
    float* g_pre   = ws + alloc((size_t)T * B * G4);
    float* pool_mW = ws + alloc((size_t)B * NI * DW);
    u16*   A2      = (u16*)(ws + alloc((size_t)T * B * 3072 / 2));   // [pool|demb] triple
    u16*   hint3   = (u16*)(ws + alloc((size_t)B * 1536 / 2));
    u16*   poolWq3t= (u16*)(ws + alloc((size_t)512 * 1536 / 2));
    u16*   poolWm3t= (u16*)(ws + alloc((size_t)512 * 1536 / 2));
    u16*   visWih3 = (u16*)(ws + alloc((size_t)G4 * 3072 / 2));      // interleaved rows
    u16*   img_mW  = (u16*)(ws + alloc((size_t)B * NI * H / 2));     // f16, dead post-loop
    u16*   ppl_mW  = (u16*)(ws + alloc((size_t)B * NP * H / 2));     // f16, dead post-loop
    u16*   img3    = (u16*)(ws + alloc((size_t)B * NI * 1536 / 2));
    u16*   ppl3    = (u16*)(ws + alloc((size_t)B * NP * 1536 / 2));
    // persistent beyond overlay reach
    u16* visWhh3   = (u16*)(ws + alloc((size_t)G4 * 3072 / 2));
    u16* langWih3  = (u16*)(ws + alloc((size_t)G4 * 4608 / 2));
    u16* langWhh3  = (u16*)(ws + alloc((size_t)G4 * 3072 / 2));
    u16* wq3t      = (u16*)(ws + alloc((size_t)2048 * 3072 / 2));
    u16* imgWm3t   = (u16*)(ws + alloc((size_t)1024 * 1536 / 2));
    u16* pplWm3t   = (u16*)(ws + alloc((size_t)1024 * 1536 / 2));
    float* c_vis   = ws + alloc((size_t)B * H);
    float* c_lang  = ws + alloc((size_t)B * H);
    u16* a3        = (u16*)(ws + alloc((size_t)2 * B * 3072 / 2));   // dbuf; a3,x4,hl3 contiguous
    u16* x4        = (u16*)(ws + alloc((size_t)2 * B * 4608 / 2));
    u16* hl3       = (u16*)(ws + alloc((size_t)2 * B * 3072 / 2));
    u16* h3_all    = (u16*)(ws + alloc((size_t)B * T * 3072 / 2));
    float* qbuf    = ws + alloc((size_t)B * 2048);
    float* gates_hh= ws + alloc((size_t)B * G4);
    float* vis_bi  = ws + alloc((size_t)G4);
    float* lang_bi = ws + alloc((size_t)G4);
    float* pool_qW = ws + alloc((size_t)B * DW);
    float* pool_sc = ws + alloc((size_t)B * NI);
    u16* projW3t   = (u16*)(ws + regionX);   // overlay over dead region

    const dim3 blk(256);

    // ---- init state ----
    zero_f<<<dim3((2 * B * H) / 256), blk, 0, stream>>>(c_vis);
    // zero a3 + x4 + hl3 (contiguous): 2*B*(3072+4608+3072) u16 = 1376256 u32
    zero_u32<<<dim3(5376), blk, 0, stream>>>((unsigned int*)a3);

    // ---- one-time splits / transposes ----
    embed_relu3<<<dim3(T * B * 64 / 256), blk, 0, stream>>>(question, emb, A2);
    permute_bias_lstm<<<dim3(16), blk, 0, stream>>>(vis_b, vis_bi);
    permute_bias_lstm<<<dim3(16), blk, 0, stream>>>(lang_b, lang_bi);
    split3_lstm<<<dim3(G4 * 128 / 256), blk, 0, stream>>>(vis_Wih, 1024, 128, visWih3, 1024, 0);
    split3_lstm<<<dim3(G4 * 128 / 256), blk, 0, stream>>>(vis_Whh, 1024, 128, visWhh3, 1024, 0);
    split3_lstm<<<dim3(G4 * 192 / 256), blk, 0, stream>>>(lang_Wih, 1536, 192, langWih3, 1536, 0);
    split3_lstm<<<dim3(G4 * 128 / 256), blk, 0, stream>>>(lang_Whh, 1024, 128, langWhh3, 1024, 0);
    split3_rows<false><<<dim3(B * NI * 64 / 256), blk, 0, stream>>>(img_feats, 512, 64, img3, 512, 0);
    split3_rows<false><<<dim3(B * NP * 64 / 256), blk, 0, stream>>>(ppl_feats, 512, 64, ppl3, 512, 0);
    split3_rows<false><<<dim3(B * 64 / 256), blk, 0, stream>>>(answer_hint, 512, 64, hint3, 512, 0);
    transpose_split3_w<<<dim3(8, 8), blk, 0, stream>>>(pool_Wq, 512, 512, poolWq3t);
    transpose_split3_w<<<dim3(8, 8), blk, 0, stream>>>(pool_Wm, 512, 512, poolWm3t);
    transpose_split3_w<<<dim3(16, 8), blk, 0, stream>>>(img_Wm, 1024, 512, imgWm3t);
    transpose_split3_w<<<dim3(16, 8), blk, 0, stream>>>(ppl_Wm, 1024, 512, pplWm3t);
    transpose_split3_w<<<dim3(16, 16), blk, 0, stream>>>(img_Wq, 1024, 1024, wq3t);
    transpose_split3_w<<<dim3(16, 16), blk, 0, stream>>>(ppl_Wq, 1024, 1024, wq3t + (size_t)1024 * 3072);

    // ---- precompute ----
    gemm3<64, 64, false, false><<<dim3(8, 2), blk, 0, stream>>>(hint3, poolWq3t, nullptr, nullptr, pool_qW, 512, 1536);
    gemm3<128, 128, false, true><<<dim3(4, 36), blk, 0, stream>>>(img3, poolWm3t, nullptr, pool_b, pool_mW, 512, 1536);
    attn_score<<<dim3(NI, B), blk, 0, stream>>>(pool_qW, 512, pool_mW, pool_v, pool_sc, NI, 512);
    attn_ctx_pool<<<dim3(B), blk, 0, stream>>>(pool_sc, img_feats, A2, NI);
    // g_pre = A2 @ visWih3^T + vis_b  (single fused GEMM, K3=3072)
    gemm3<128, 128, false, true><<<dim3(32, 20), blk, 0, stream>>>(A2, visWih3, nullptr, vis_bi, g_pre, G4, 3072);
    // attention memories -> f16 (+bias folded)
    gemm3<128, 128, false, true, 0, true><<<dim3(8, 36), blk, 0, stream>>>(img3, imgWm3t, nullptr, img_b, img_mW, H, 1536);
    gemm3<128, 128, false, true, 0, true><<<dim3(8, 100), blk, 0, stream>>>(ppl3, pplWm3t, nullptr, ppl_b, ppl_mW, H, 1536);

    // ---- sequential decode: combo[lang(t-1) || vis(t)] -> q_hh(t) -> attn(t) ----
    for (int t = 0; t <= T; ++t) {
        u16* x4_prev = x4 + (size_t)((t + 1) & 1) * B * 4608;   // x4(t-1): lang A input
        u16* x4_cur  = x4 + (size_t)(t & 1) * B * 4608;         // x4(t)
        u16* vis_A   = a3 + (size_t)(t & 1) * B * 3072;         // h_vis(t-1) triple
        u16* vis_o1  = a3 + (size_t)((t + 1) & 1) * B * 3072;   // h_vis(t) triple
        u16* hl_prev = hl3 + (size_t)((t + 1) & 1) * B * 3072;  // h_lang(t-1) triple
        u16* hl_out  = hl_prev;                                 // lang(t-1) writes h_lang(t-1)
        const float* gp = g_pre + (size_t)(t < T ? t : 0) * B * G4;
        step_combo<<<dim3(64, 2, 2), blk, 0, stream>>>(
            x4_prev, langWih3, gates_hh, c_lang, hl_out, h3_all,
            vis_A, visWhh3, gp, c_vis, vis_o1, x4_cur, t);
        if (t < T) {
            // q(t) from h_vis(t); lang-hh for step t: Whh @ h_lang(t-1) + bias
            gemm_q_hh<<<dim3(512), blk, 0, stream>>>(
                vis_o1, wq3t, qbuf, hl_prev, langWhh3, lang_bi, gates_hh);
            attn_fused<<<dim3(B), dim3(512), 0, stream>>>(qbuf, img_mW, ppl_mW, img_v, ppl_v,
                                                          img_feats, ppl_feats, x4_cur);
        }
    }

    // ---- deferred projection (super-tiled for L3 reuse) ----
    transpose_split3_w<<<dim3(313, 16), blk, 0, stream>>>(proj_W, V, 1024, projW3t);
    gemm3<128, 128, false, true, 10><<<dim3(157, 20), blk, 0, stream>>>(
        h3_all, projW3t, nullptr, proj_b, out, V, 3072);
    logsm_argmax<<<dim3(B * T), blk, 0, stream>>>(out);
}

// Round 13
// 3331.741 us; speedup vs baseline: 1.2413x; 1.0263x over previous
//
#include <hip/hip_runtime.h>
#include <cstddef>
#include <cstdint>

using u16 = unsigned short;
typedef float    f32x4 __attribute__((ext_vector_type(4)));
typedef _Float16 f16x8 __attribute__((ext_vector_type(8)));
typedef u16      us8   __attribute__((ext_vector_type(8)));

constexpr int B  = 128;
constexpr int T  = 20;
constexpr int V  = 20000;
constexpr int DW = 512;
constexpr int H  = 1024;
constexpr int G4 = 4096;
constexpr int NI = 36;
constexpr int NP = 100;
constexpr int SOS = 1;

__device__ __forceinline__ float sigf(float x) { return 1.0f / (1.0f + expf(-x)); }
__device__ __forceinline__ u16 f16bits(_Float16 h) { u16 u; __builtin_memcpy(&u, &h, 2); return u; }
__device__ __forceinline__ float h2f(u16 u) { _Float16 h; __builtin_memcpy(&h, &u, 2); return (float)h; }

// f16x3 split: x ~= hi + lo as triples; one K-expanded f16 GEMM computes
// hi*hi + lo*hi + hi*lo (error ~2^-22). A: [hi, lo*64, hi/64]; W: [hi, hi/64, lo*64]
template<bool WSIDE>
__device__ __forceinline__ void split1(float x, u16& b0, u16& b1, u16& b2) {
    _Float16 h  = (_Float16)x;
    float    hf = (float)h;
    _Float16 lo = (_Float16)((x - hf) * 64.0f);
    _Float16 hs = (_Float16)(hf * (1.0f / 64.0f));
    b0 = f16bits(h);
    if constexpr (WSIDE) { b1 = f16bits(hs); b2 = f16bits(lo); }
    else                 { b1 = f16bits(lo); b2 = f16bits(hs); }
}

// ---------------------------------------------------------------------------
// Generic MFMA GEMM (precompute + proj): C[M,N] = A3[M,K3] x B3t[N,K3]^T.
// BK=64, 4 waves 2x2, software-pipelined. NSW>0: super-tile remap for L3 reuse.
// OUTF16: write C as f16.
// ---------------------------------------------------------------------------
template<int BM, int BN, bool HAS_ADD, bool HAS_BIAS, int NSW = 0, bool OUTF16 = false>
__global__ __launch_bounds__(256)
void gemm3(const u16* __restrict__ A, const u16* __restrict__ Bt,
           const float* __restrict__ Add, const float* __restrict__ bias,
           void* __restrict__ Cv, int N, int K3)
{
    __shared__ __align__(16) u16 As[BM * 64];
    __shared__ __align__(16) u16 Bs[BN * 64];
    constexpr int FR = BM / 32, FC = BN / 32, PA = BM / 32, PB = BN / 32;
    const int tid  = threadIdx.x;
    int bx = blockIdx.x, by = blockIdx.y;
    if constexpr (NSW > 0) {
        const int nt = (int)gridDim.x, mt = (int)gridDim.y;
        const int lin = by * nt + bx;
        const int sc0 = (lin / (NSW * mt)) * NSW;
        const int w   = (NSW < nt - sc0) ? NSW : (nt - sc0);
        const int r   = lin - sc0 * mt;
        bx = sc0 + r % w;
        by = r / w;
    }
    const int bm   = by * BM, bn = bx * BN;
    const int lane = tid & 63, wid = tid >> 6;
    const int wm   = (wid >> 1) * (BM / 2), wn = (wid & 1) * (BN / 2);
    const int srow = tid >> 3;
    const int scol = (tid & 7) * 8;

    f32x4 acc[FR][FC] = {};
    us8 ra[PA], rb[PB];

    auto ldg = [&](int k0) {
#pragma unroll
        for (int p = 0; p < PA; ++p)
            ra[p] = *(const us8*)(A + (size_t)(bm + p * 32 + srow) * K3 + k0 + scol);
#pragma unroll
        for (int p = 0; p < PB; ++p) {
            int n = bn + p * 32 + srow; if (n > N - 1) n = N - 1;
            rb[p] = *(const us8*)(Bt + (size_t)n * K3 + k0 + scol);
        }
    };
    ldg(0);

    for (int k0 = 0; k0 < K3; k0 += 64) {
        __syncthreads();
#pragma unroll
        for (int p = 0; p < PA; ++p) {
            const int row = p * 32 + srow;
            *(us8*)((char*)As + row * 128 + ((scol * 2) ^ ((row & 7) << 4))) = ra[p];
        }
#pragma unroll
        for (int p = 0; p < PB; ++p) {
            const int row = p * 32 + srow;
            *(us8*)((char*)Bs + row * 128 + ((scol * 2) ^ ((row & 7) << 4))) = rb[p];
        }
        __syncthreads();
        if (k0 + 64 < K3) ldg(k0 + 64);
#pragma unroll
        for (int ks = 0; ks < 2; ++ks) {
            f16x8 af[FR], bf[FC];
#pragma unroll
            for (int m = 0; m < FR; ++m) {
                const int row = wm + m * 16 + (lane & 15);
                const int cb  = (ks * 64 + ((lane >> 4) << 4)) ^ ((row & 7) << 4);
                af[m] = *(const f16x8*)((const char*)As + row * 128 + cb);
            }
#pragma unroll
            for (int n = 0; n < FC; ++n) {
                const int row = wn + n * 16 + (lane & 15);
                const int cb  = (ks * 64 + ((lane >> 4) << 4)) ^ ((row & 7) << 4);
                bf[n] = *(const f16x8*)((const char*)Bs + row * 128 + cb);
            }
#pragma unroll
            for (int m = 0; m < FR; ++m)
#pragma unroll
                for (int n = 0; n < FC; ++n)
                    acc[m][n] = __builtin_amdgcn_mfma_f32_16x16x32_f16(af[m], bf[n], acc[m][n], 0, 0, 0);
        }
    }
#pragma unroll
    for (int m = 0; m < FR; ++m) {
        const int r0 = bm + wm + m * 16 + ((lane >> 4) << 2);
#pragma unroll
        for (int n = 0; n < FC; ++n) {
            const int c = bn + wn + n * 16 + (lane & 15);
            if (c < N) {
#pragma unroll
                for (int j = 0; j < 4; ++j) {
                    float v = acc[m][n][j];
                    if constexpr (HAS_ADD)  v += Add[(size_t)(r0 + j) * N + c];
                    if constexpr (HAS_BIAS) v += bias[c];
                    if constexpr (OUTF16)
                        ((u16*)Cv)[(size_t)(r0 + j) * N + c] = f16bits((_Float16)v);
                    else
                        ((float*)Cv)[(size_t)(r0 + j) * N + c] = v;
                }
            }
        }
    }
}

// ---------------------------------------------------------------------------
// In-loop GEMM core (BM=64, BN/BK params), 256 threads, 4 waves each 16 rows x
// BN cols. EPI=0: plain f32 C. EPI=1: vis-LSTM (+Add=g_pre). EPI=2: lang-LSTM
// (+Add=gates_hh). EPI=3: plain f32 C + bias (interleaved col space).
// ---------------------------------------------------------------------------
template<int EPI, int BN, int BK>
__device__ __forceinline__ void gemm_core(
    u16* As, u16* Bs,
    const u16* A, const u16* Bt,
    const float* Add, const float* bias,
    float* CS, u16* o1, u16* o2,
    int N, int K3, int t, int bx, int by)
{
    constexpr int NA8  = BK / 32;
    constexpr int TPRB = 256 / BN;
    constexpr int NB8  = (BK / TPRB) / 8;
    constexpr int NFC  = BN / 16;
    const int tid  = threadIdx.x;
    const int bn   = bx * BN, bm = by * 64;
    const int lane = tid & 63, wv = tid >> 6;
    const int rowA = tid >> 2;
    const int scA  = (tid & 3) * (BK / 4);
    const int rowB = tid / TPRB;
    const int scB  = (tid % TPRB) * (BK / TPRB);
    const int swzA = (rowA & 7) << 4;
    const int swzB = (rowB & 7) << 4;
    const u16* Ap = A  + (size_t)(bm + rowA) * K3 + scA;
    const u16* Bp = Bt + (size_t)(bn + rowB) * K3 + scB;
    char* Awp = (char*)As + rowA * (BK * 2);
    char* Bwp = (char*)Bs + rowB * (BK * 2);
    const int arow = wv * 16 + (lane & 15);
    const char* Arp = (const char*)As + arow * (BK * 2);
    const int aswz = (arow & 7) << 4;
    const int jl   = lane & 15;

    f32x4 acc[NFC] = {};
    us8 ra[NA8], rb[NB8];
#pragma unroll
    for (int i = 0; i < NA8; ++i) ra[i] = *(const us8*)(Ap + 8 * i);
#pragma unroll
    for (int i = 0; i < NB8; ++i) rb[i] = *(const us8*)(Bp + 8 * i);

    for (int k0 = 0; k0 < K3; k0 += BK) {
        __syncthreads();
#pragma unroll
        for (int i = 0; i < NA8; ++i)
            *(us8*)(Awp + ((scA * 2 + 16 * i) ^ swzA)) = ra[i];
#pragma unroll
        for (int i = 0; i < NB8; ++i)
            *(us8*)(Bwp + ((scB * 2 + 16 * i) ^ swzB)) = rb[i];
        __syncthreads();
        if (k0 + BK < K3) {
#pragma unroll
            for (int i = 0; i < NA8; ++i) ra[i] = *(const us8*)(Ap + k0 + BK + 8 * i);
#pragma unroll
            for (int i = 0; i < NB8; ++i) rb[i] = *(const us8*)(Bp + k0 + BK + 8 * i);
        }
#pragma unroll
        for (int ks = 0; ks < BK / 32; ++ks) {
            const int cb = ks * 64 + ((lane >> 4) << 4);
            const f16x8 af = *(const f16x8*)(Arp + (cb ^ aswz));
#pragma unroll
            for (int g = 0; g < NFC; ++g) {
                const int brow = g * 16 + jl;
                const f16x8 bf = *(const f16x8*)((const char*)Bs + brow * (BK * 2) + (cb ^ ((brow & 7) << 4)));
                acc[g] = __builtin_amdgcn_mfma_f32_16x16x32_f16(af, bf, acc[g], 0, 0, 0);
            }
        }
    }
    const int rb0 = bm + wv * 16 + ((lane >> 4) << 2);
    if constexpr (EPI == 0 || EPI == 3) {
#pragma unroll
        for (int g = 0; g < NFC; ++g) {
            const int c = bn + g * 16 + jl;
#pragma unroll
            for (int jj = 0; jj < 4; ++jj) {
                float v = acc[g][jj];
                if constexpr (EPI == 3) v += bias[c];
                CS[(size_t)(rb0 + jj) * N + c] = v;
            }
        }
    } else {
        const int j = bx * 16 + jl;
#pragma unroll
        for (int jj = 0; jj < 4; ++jj) {
            const int b = rb0 + jj;
            float gi = acc[0][jj], gf = acc[1][jj], gg = acc[2][jj], go = acc[3][jj];
            {
                const float* ap = Add + (size_t)b * 4096 + bn + jl;
                gi += ap[0]; gf += ap[16]; gg += ap[32]; go += ap[48];
            }
            const float c = sigf(gf) * CS[b * 1024 + j] + sigf(gi) * tanhf(gg);
            const float h = sigf(go) * tanhf(c);
            CS[b * 1024 + j] = c;
            u16 b0, b1, b2; split1<false>(h, b0, b1, b2);
            if constexpr (EPI == 1) {
                u16* a = o1 + (size_t)b * 3072 + j;           // a3: h_vis triple
                a[0] = b0; a[1024] = b1; a[2048] = b2;
                u16* x = o2 + (size_t)b * 4608 + 512 + j;     // x4 h_vis slot (Kt=1536)
                x[0] = b0; x[1536] = b1; x[3072] = b2;
            } else {                                          // EPI == 2
                u16* hl = o1 + (size_t)b * 3072 + j;          // hl3: h_lang triple
                hl[0] = b0; hl[1024] = b1; hl[2048] = b2;
                u16* hh = o2 + ((size_t)b * T + t) * 3072 + j; // h3_all
                hh[0] = b0; hh[1024] = b1; hh[2048] = b2;
            }
        }
    }
}

// q + lang-hh fused launch: blocks [0,256) q(t) (BN=16), [256,512) hh (BN=32).
// hh: gates_hh = hl3(t-1) @ langWhh3^T + lang_bi (interleaved cols).
__global__ __launch_bounds__(256)
void gemm_q_hh(const u16* __restrict__ a3_new, const u16* __restrict__ wq3t,
               float* qbuf,
               const u16* __restrict__ hl_prev, const u16* __restrict__ langWhh3,
               const float* __restrict__ lang_bi, float* gates_hh)
{
    __shared__ __align__(16) u16 As[64 * 384];
    __shared__ __align__(16) u16 Bs[32 * 384];
    const int blk = blockIdx.x;
    if (blk < 256) {
        gemm_core<0, 16, 384>(As, Bs, a3_new, wq3t, nullptr, nullptr,
                              qbuf, nullptr, nullptr, 2048, 3072, 0,
                              blk & 127, blk >> 7);
    } else {
        const int b2 = blk - 256;
        gemm_core<3, 32, 384>(As, Bs, hl_prev, langWhh3, nullptr, lang_bi,
                              gates_hh, nullptr, nullptr, 4096, 3072, 0,
                              b2 & 127, b2 >> 7);
    }
}

// Combined step kernel: z=0 -> lang(t-1) K=4608 (skip t==0), z=1 -> vis(t)
// (skip t==T). grid (64,2,2), 256 threads, BK=384 (96 KB LDS).
__global__ __launch_bounds__(256)
void step_combo(const u16* __restrict__ lang_A, const u16* __restrict__ langWih3,
                const float* __restrict__ gates_hh, float* c_lang,
                u16* hl_out, u16* h3_all,
                const u16* __restrict__ vis_A, const u16* __restrict__ visWhh3,
                const float* __restrict__ g_pre_t, float* c_vis,
                u16* vis_o1, u16* vis_o2, int t)
{
    __shared__ __align__(16) u16 As[64 * 384];
    __shared__ __align__(16) u16 Bs[64 * 384];
    if (blockIdx.z == 0) {
        if (t >= 1)
            gemm_core<2, 64, 384>(As, Bs, lang_A, langWih3, gates_hh, nullptr,
                                  c_lang, hl_out, h3_all, G4, 4608, t - 1,
                                  blockIdx.x, blockIdx.y);
    } else {
        if (t < T)
            gemm_core<1, 64, 384>(As, Bs, vis_A, visWhh3, g_pre_t, nullptr,
                                  c_vis, vis_o1, vis_o2, G4, 3072, t,
                                  blockIdx.x, blockIdx.y);
    }
}

// ---------------------------------------------------------------------------
// Row-major split: src f32 [M][ld] -> triple cols in out [M][3*Kt].
template<bool WSIDE>
__global__ __launch_bounds__(256)
void split3_rows(const float* __restrict__ src, int ld, int K8,
                 u16* __restrict__ out, int Kt, int coloff)
{
    const int idx = blockIdx.x * 256 + threadIdx.x;
    const int r = idx / K8, kk = (idx - r * K8) * 8;
    const float* s = src + (size_t)r * ld + kk;
    const float4 x0 = *(const float4*)s, x1 = *(const float4*)(s + 4);
    float xs[8] = {x0.x, x0.y, x0.z, x0.w, x1.x, x1.y, x1.z, x1.w};
    us8 h, m, l;
#pragma unroll
    for (int j = 0; j < 8; ++j) { u16 a, b, c; split1<WSIDE>(xs[j], a, b, c); h[j]=a; m[j]=b; l[j]=c; }
    u16* o = out + (size_t)r * (3 * Kt) + coloff + kk;
    *(us8*)o = h; *(us8*)(o + Kt) = m; *(us8*)(o + 2 * Kt) = l;
}

// LSTM weight split, gate-interleaved output rows: src row r = g*1024+j ->
// out row (j>>4)*64 + g*16 + (j&15). W-side triple.
__global__ __launch_bounds__(256)
void split3_lstm(const float* __restrict__ src, int ld, int K8,
                 u16* __restrict__ out, int Kt, int coloff)
{
    const int idx = blockIdx.x * 256 + threadIdx.x;
    const int r = idx / K8, kk = (idx - r * K8) * 8;
    const int g = r >> 10, j = r & 1023;
    const int orow = ((j >> 4) << 6) + (g << 4) + (j & 15);
    const float* s = src + (size_t)r * ld + kk;
    const float4 x0 = *(const float4*)s, x1 = *(const float4*)(s + 4);
    float xs[8] = {x0.x, x0.y, x0.z, x0.w, x1.x, x1.y, x1.z, x1.w};
    us8 h, m, l;
#pragma unroll
    for (int jj = 0; jj < 8; ++jj) { u16 a, b, c; split1<true>(xs[jj], a, b, c); h[jj]=a; m[jj]=b; l[jj]=c; }
    u16* o = out + (size_t)orow * (3 * Kt) + coloff + kk;
    *(us8*)o = h; *(us8*)(o + Kt) = m; *(us8*)(o + 2 * Kt) = l;
}

// bias permute into gate-interleaved col space
__global__ __launch_bounds__(256)
void permute_bias_lstm(const float* __restrict__ b, float* __restrict__ out)
{
    const int c = blockIdx.x * 256 + threadIdx.x;
    const int jg = c >> 6, g = (c >> 4) & 3, jlo = c & 15;
    out[c] = b[g * 1024 + jg * 16 + jlo];
}

// Transpose + W-side split: W f32 [K][N] -> out u16 [N][3K].
__global__ __launch_bounds__(256)
void transpose_split3_w(const float* __restrict__ W, int N, int K,
                        u16* __restrict__ out)
{
    const int n0 = blockIdx.x * 64, k0 = blockIdx.y * 64;
    const int tid = threadIdx.x;
    __shared__ float ts[64][65];
    for (int i = 0; i < 16; ++i) {
        const int idx = i * 256 + tid;
        const int kl = idx >> 6, nl = idx & 63;
        float v = 0.f;
        if (n0 + nl < N) v = W[(size_t)(k0 + kl) * N + n0 + nl];
        ts[nl][kl] = v;
    }
    __syncthreads();
    for (int i = 0; i < 2; ++i) {
        const int idx = i * 256 + tid;
        const int nl = idx >> 3, kc = (idx & 7) * 8;
        if (n0 + nl < N) {
            us8 h, m, l;
#pragma unroll
            for (int j = 0; j < 8; ++j) {
                u16 a, b, c; split1<true>(ts[nl][kc + j], a, b, c);
                h[j] = a; m[j] = b; l[j] = c;
            }
            u16* o = out + (size_t)(n0 + nl) * (3 * K) + k0 + kc;
            *(us8*)o = h; *(us8*)(o + K) = m; *(us8*)(o + 2 * K) = l;
        }
    }
}

// embedding lookup + relu + A-side split -> A2 rows [T*B][3072], demb segment
// at coloff 512 of a Kt=1024 triple ([pool(0:512) | demb(512:1024)]).
__global__ __launch_bounds__(256)
void embed_relu3(const int* __restrict__ question, const float* __restrict__ emb,
                 u16* __restrict__ A2)
{
    const int idx = blockIdx.x * 256 + threadIdx.x;
    const int r = idx >> 6, kk = (idx & 63) * 8;
    const int t = r / B, b = r - t * B;
    const int tok = (t == 0) ? SOS : question[b * T + t - 1];
    const float* s = emb + (size_t)tok * DW + kk;
    const float4 x0 = *(const float4*)s, x1 = *(const float4*)(s + 4);
    float xs[8] = {x0.x, x0.y, x0.z, x0.w, x1.x, x1.y, x1.z, x1.w};
    us8 h, m, l;
#pragma unroll
    for (int j = 0; j < 8; ++j) {
        u16 a, b2, c; split1<false>(fmaxf(xs[j], 0.f), a, b2, c);
        h[j] = a; m[j] = b2; l[j] = c;
    }
    u16* o = A2 + (size_t)r * 3072 + 512 + kk;
    *(us8*)o = h; *(us8*)(o + 1024) = m; *(us8*)(o + 2048) = l;
}

// pool attention scores (f32 mW)
__global__ __launch_bounds__(256)
void attn_score(const float* __restrict__ q, int qld,
                const float* __restrict__ mW, const float* __restrict__ v,
                float* __restrict__ score, int Nn, int Hd)
{
    const int n = blockIdx.x, b = blockIdx.y;
    const float* qp = q + (size_t)b * qld;
    const float* mp = mW + ((size_t)b * Nn + n) * Hd;
    float s = 0.f;
    for (int h = threadIdx.x; h < Hd; h += 256)
        s += tanhf(qp[h] + mp[h]) * v[h];
    __shared__ float red[4];
    const int lane = threadIdx.x & 63, wv = threadIdx.x >> 6;
    for (int o = 32; o; o >>= 1) s += __shfl_down(s, o, 64);
    if (lane == 0) red[wv] = s;
    __syncthreads();
    if (threadIdx.x == 0) score[(size_t)b * Nn + n] = red[0] + red[1] + red[2] + red[3];
}

// pool ctx -> broadcast triple into A2 pool segment (coloff 0) for all T rows
__global__ __launch_bounds__(256)
void attn_ctx_pool(const float* __restrict__ score, const float* __restrict__ m,
                   u16* __restrict__ A2, int Nn)
{
    constexpr int D = 512;
    const int b = blockIdx.x;
    __shared__ float aw[128];
    __shared__ float red[8];
    const int tid = threadIdx.x, lane = tid & 63, wv = tid >> 6;
    float mx = -3.4e38f;
    for (int n = tid; n < Nn; n += 256) mx = fmaxf(mx, score[(size_t)b * Nn + n]);
    for (int o = 32; o; o >>= 1) mx = fmaxf(mx, __shfl_down(mx, o, 64));
    if (lane == 0) red[wv] = mx;
    __syncthreads();
    mx = fmaxf(fmaxf(red[0], red[1]), fmaxf(red[2], red[3]));
    float se = 0.f;
    for (int n = tid; n < Nn; n += 256) {
        float e = expf(score[(size_t)b * Nn + n] - mx);
        aw[n] = e; se += e;
    }
    for (int o = 32; o; o >>= 1) se += __shfl_down(se, o, 64);
    if (lane == 0) red[4 + wv] = se;
    __syncthreads();
    const float inv = 1.0f / (red[4] + red[5] + red[6] + red[7]);
    for (int d = tid; d < D; d += 256) {
        float s = 0.f;
        for (int n = 0; n < Nn; ++n) s += aw[n] * m[((size_t)b * Nn + n) * D + d];
        s *= inv;
        u16 b0, b1, b2; split1<false>(s, b0, b1, b2);
        for (int tt = 0; tt < T; ++tt) {
            u16* o = A2 + ((size_t)tt * B + b) * 3072 + d;
            o[0] = b0; o[1024] = b1; o[2048] = b2;
        }
    }
}

// Fused in-loop attention, 512 threads (8 waves); mW in f16, feats in f32.
// Writes x4 attn slot (Kt=1536).
__global__ __launch_bounds__(512)
void attn_fused(const float* __restrict__ qbuf,
                const u16* __restrict__ img_mW, const u16* __restrict__ ppl_mW,
                const float* __restrict__ img_v, const float* __restrict__ ppl_v,
                const float* __restrict__ img_feats, const float* __restrict__ ppl_feats,
                u16* __restrict__ x4)
{
    const int b = blockIdx.x;
    const int tid = threadIdx.x, lane = tid & 63, wv = tid >> 6;
    __shared__ float qs[2048];
    __shared__ float vs[2048];
    __shared__ float aw[136];
    __shared__ float awn[136];

    for (int i = tid; i < 2048; i += 512) {
        qs[i] = qbuf[(size_t)b * 2048 + i];
        vs[i] = (i < 1024) ? img_v[i] : ppl_v[i - 1024];
    }
    __syncthreads();

    for (int n = wv; n < NI; n += 8) {
        const u16* mp = img_mW + ((size_t)b * NI + n) * 1024;
        float s = 0.f;
#pragma unroll
        for (int u = 0; u < 2; ++u) {
            const int h = (lane + 64 * u) * 8;
            const us8 m8 = *(const us8*)(mp + h);
#pragma unroll
            for (int j = 0; j < 8; ++j)
                s += tanhf(qs[h + j] + h2f(m8[j])) * vs[h + j];
        }
        for (int o = 1; o < 64; o <<= 1) s += __shfl_xor(s, o, 64);
        if (lane == 0) aw[n] = s;
    }
    for (int n = wv; n < NP; n += 8) {
        const u16* mp = ppl_mW + ((size_t)b * NP + n) * 1024;
        float s = 0.f;
#pragma unroll
        for (int u = 0; u < 2; ++u) {
            const int h = (lane + 64 * u) * 8;
            const us8 m8 = *(const us8*)(mp + h);
#pragma unroll
            for (int j = 0; j < 8; ++j)
                s += tanhf(qs[1024 + h + j] + h2f(m8[j])) * vs[1024 + h + j];
        }
        for (int o = 1; o < 64; o <<= 1) s += __shfl_xor(s, o, 64);
        if (lane == 0) aw[36 + n] = s;
    }
    __syncthreads();

    if (wv == 0) {
        const float x = (lane < NI) ? aw[lane] : -3.4e38f;
        float mx = x;
        for (int o = 1; o < 64; o <<= 1) mx = fmaxf(mx, __shfl_xor(mx, o, 64));
        const float e = (lane < NI) ? expf(x - mx) : 0.f;
        float ss = e;
        for (int o = 1; o < 64; o <<= 1) ss += __shfl_xor(ss, o, 64);
        if (lane < NI) awn[lane] = e / ss;
    } else if (wv == 1) {
        const float x0 = aw[36 + lane];
        const float x1 = (lane < NP - 64) ? aw[100 + lane] : -3.4e38f;
        float mx = fmaxf(x0, x1);
        for (int o = 1; o < 64; o <<= 1) mx = fmaxf(mx, __shfl_xor(mx, o, 64));
        const float e0 = expf(x0 - mx);
        const float e1 = (lane < NP - 64) ? expf(x1 - mx) : 0.f;
        float ss = e0 + e1;
        for (int o = 1; o < 64; o <<= 1) ss += __shfl_xor(ss, o, 64);
        awn[36 + lane] = e0 / ss;
        if (lane < NP - 64) awn[100 + lane] = e1 / ss;
    }
    __syncthreads();

    {
        const int d = tid;   // 512 threads == D
        float s = 0.f;
        const float* ip = img_feats + (size_t)b * NI * 512 + d;
#pragma unroll 4
        for (int n = 0; n < NI; ++n) s += awn[n] * ip[n * 512];
        const float* pp = ppl_feats + (size_t)b * NP * 512 + d;
#pragma unroll 4
        for (int n = 0; n < NP; ++n) s += awn[36 + n] * pp[n * 512];
        u16 b0, b1, b2; split1<false>(s, b0, b1, b2);
        u16* o = x4 + (size_t)b * 4608 + d;
        o[0] = b0; o[1536] = b1; o[3072] = b2;
    }
}

__global__ __launch_bounds__(256)
void zero_f(float* __restrict__ p) { p[blockIdx.x * 256 + threadIdx.x] = 0.f; }

__global__ __launch_bounds__(256)
void zero_u32(unsigned int* __restrict__ p) { p[blockIdx.x * 256 + threadIdx.x] = 0u; }

// online log_softmax over out rows [r][V], argmax -> out[BTV+r]
__global__ __launch_bounds__(256)
void logsm_argmax(float* __restrict__ out)
{
    const int r = blockIdx.x;
    float* row = out + (size_t)r * V;
    const int tid = threadIdx.x, lane = tid & 63, wv = tid >> 6;
    float m = -3.4e38f, s = 0.f; int mi = 0;
    for (int i4 = tid; i4 < V / 4; i4 += 256) {
        const float4 x4 = ((const float4*)row)[i4];
        const float xs[4] = {x4.x, x4.y, x4.z, x4.w};
#pragma unroll
        for (int j = 0; j < 4; ++j) {
            const float x = xs[j];
            if (x > m) { s = s * expf(m - x) + 1.f; m = x; mi = i4 * 4 + j; }
            else       s += expf(x - m);
        }
    }
    for (int o = 1; o < 64; o <<= 1) {
        const float m2 = __shfl_xor(m, o, 64);
        const float s2 = __shfl_xor(s, o, 64);
        const int  mi2 = __shfl_xor(mi, o, 64);
        if (m2 > m || (m2 == m && mi2 < mi)) { s = s2 + s * expf(m - m2); m = m2; mi = mi2; }
        else s += s2 * expf(m2 - m);
    }
    __shared__ float sm[4], ssm[4]; __shared__ int smi[4];
    __shared__ float lse_sh; __shared__ int mi_sh;
    if (lane == 0) { sm[wv] = m; ssm[wv] = s; smi[wv] = mi; }
    __syncthreads();
    if (tid == 0) {
        float M = sm[0], S = ssm[0]; int MI = smi[0];
        for (int w = 1; w < 4; ++w) {
            if (sm[w] > M || (sm[w] == M && smi[w] < MI)) { S = ssm[w] + S * expf(M - sm[w]); M = sm[w]; MI = smi[w]; }
            else S += ssm[w] * expf(sm[w] - M);
        }
        lse_sh = M + logf(S); mi_sh = MI;
    }
    __syncthreads();
    const float lse = lse_sh;
    for (int i4 = tid; i4 < V / 4; i4 += 256) {
        float4 x4 = ((const float4*)row)[i4];
        x4.x -= lse; x4.y -= lse; x4.z -= lse; x4.w -= lse;
        ((float4*)row)[i4] = x4;
    }
    if (tid == 0) out[(size_t)B * T * V + r] = (float)mi_sh;
}

// ---------------------------------------------------------------------------
extern "C" void kernel_launch(void* const* d_in, const int* in_sizes, int n_in,
                              void* d_out, int out_size, void* d_ws, size_t ws_size,
                              hipStream_t stream)
{
    (void)in_sizes; (void)n_in; (void)out_size; (void)ws_size;

    const float* img_feats   = (const float*)d_in[0];
    const float* ppl_feats   = (const float*)d_in[1];
    const float* answer_hint = (const float*)d_in[2];
    const int*   question    = (const int*)d_in[3];
    const float* emb         = (const float*)d_in[4];
    const float* pool_Wq     = (const float*)d_in[5];
    const float* pool_Wm     = (const float*)d_in[6];
    const float* pool_b      = (const float*)d_in[7];
    const float* pool_v      = (const float*)d_in[8];
    const float* img_Wq      = (const float*)d_in[9];
    const float* img_Wm      = (const float*)d_in[10];
    const float* img_b       = (const float*)d_in[11];
    const float* img_v       = (const float*)d_in[12];
    const float* ppl_Wq      = (const float*)d_in[13];
    const float* ppl_Wm      = (const float*)d_in[14];
    const float* ppl_b       = (const float*)d_in[15];
    const float* ppl_v       = (const float*)d_in[16];
    const float* vis_Wih     = (const float*)d_in[17];
    const float* vis_Whh     = (const float*)d_in[18];
    const float* vis_b       = (const float*)d_in[19];
    const float* lang_Wih    = (const float*)d_in[20];
    const float* lang_Whh    = (const float*)d_in[21];
    const float* lang_b      = (const float*)d_in[22];
    const float* proj_W      = (const float*)d_in[23];
    const float* proj_b      = (const float*)d_in[24];

    float* out = (float*)d_out;
    float* ws  = (float*)d_ws;

    size_t off = 0;
    auto alloc = [&](size_t nf) { size_t r = off; off += (nf + 63) & ~(size_t)63; return r; };
    // Region X: dead after the decode loop; projW3t overlaid post-loop.
    const size_t regionX = off;
    float* g_pre   = ws + alloc((size_t)T * B * G4);
    float* pool_mW = ws + alloc((size_t)B * NI * DW);
    u16*   A2      = (u16*)(ws + alloc((size_t)T * B * 3072 / 2));   // [pool|demb] triple
    u16*   hint3   = (u16*)(ws + alloc((size_t)B * 1536 / 2));
    u16*   poolWq3t= (u16*)(ws + alloc((size_t)512 * 1536 / 2));
    u16*   poolWm3t= (u16*)(ws + alloc((size_t)512 * 1536 / 2));
    u16*   visWih3 = (u16*)(ws + alloc((size_t)G4 * 3072 / 2));      // interleaved rows
    u16*   img_mW  = (u16*)(ws + alloc((size_t)B * NI * H / 2));     // f16, dead post-loop
    u16*   ppl_mW  = (u16*)(ws + alloc((size_t)B * NP * H / 2));     // f16, dead post-loop
    u16*   img3    = (u16*)(ws + alloc((size_t)B * NI * 1536 / 2));
    u16*   ppl3    = (u16*)(ws + alloc((size_t)B * NP * 1536 / 2));
    // persistent beyond overlay reach
    u16* visWhh3   = (u16*)(ws + alloc((size_t)G4 * 3072 / 2));
    u16* langWih3  = (u16*)(ws + alloc((size_t)G4 * 4608 / 2));
    u16* langWhh3  = (u16*)(ws + alloc((size_t)G4 * 3072 / 2));
    u16* wq3t      = (u16*)(ws + alloc((size_t)2048 * 3072 / 2));
    u16* imgWm3t   = (u16*)(ws + alloc((size_t)1024 * 1536 / 2));
    u16* pplWm3t   = (u16*)(ws + alloc((size_t)1024 * 1536 / 2));
    float* c_vis   = ws + alloc((size_t)B * H);
    float* c_lang  = ws + alloc((size_t)B * H);
    u16* a3        = (u16*)(ws + alloc((size_t)2 * B * 3072 / 2));   // dbuf; a3,x4,hl3 contiguous
    u16* x4        = (u16*)(ws + alloc((size_t)2 * B * 4608 / 2));
    u16* hl3       = (u16*)(ws + alloc((size_t)2 * B * 3072 / 2));
    u16* h3_all    = (u16*)(ws + alloc((size_t)B * T * 3072 / 2));
    float* qbuf    = ws + alloc((size_t)B * 2048);
    float* gates_hh= ws + alloc((size_t)B * G4);
    float* vis_bi  = ws + alloc((size_t)G4);
    float* lang_bi = ws + alloc((size_t)G4);
    float* pool_qW = ws + alloc((size_t)B * DW);
    float* pool_sc = ws + alloc((size_t)B * NI);
    u16* projW3t   = (u16*)(ws + regionX);   // overlay over dead region

    const dim3 blk(256);

    // ---- init state ----
    zero_f<<<dim3((2 * B * H) / 256), blk, 0, stream>>>(c_vis);
    // zero a3 + x4 + hl3 (contiguous): 2*B*(3072+4608+3072) u16 = 1376256 u32
    zero_u32<<<dim3(5376), blk, 0, stream>>>((unsigned int*)a3);

    // ---- one-time splits / transposes ----
    embed_relu3<<<dim3(T * B * 64 / 256), blk, 0, stream>>>(question, emb, A2);
    permute_bias_lstm<<<dim3(16), blk, 0, stream>>>(vis_b, vis_bi);
    permute_bias_lstm<<<dim3(16), blk, 0, stream>>>(lang_b, lang_bi);
    split3_lstm<<<dim3(G4 * 128 / 256), blk, 0, stream>>>(vis_Wih, 1024, 128, visWih3, 1024, 0);
    split3_lstm<<<dim3(G4 * 128 / 256), blk, 0, stream>>>(vis_Whh, 1024, 128, visWhh3, 1024, 0);
    split3_lstm<<<dim3(G4 * 192 / 256), blk, 0, stream>>>(lang_Wih, 1536, 192, langWih3, 1536, 0);
    split3_lstm<<<dim3(G4 * 128 / 256), blk, 0, stream>>>(lang_Whh, 1024, 128, langWhh3, 1024, 0);
    split3_rows<false><<<dim3(B * NI * 64 / 256), blk, 0, stream>>>(img_feats, 512, 64, img3, 512, 0);
    split3_rows<false><<<dim3(B * NP * 64 / 256), blk, 0, stream>>>(ppl_feats, 512, 64, ppl3, 512, 0);
    split3_rows<false><<<dim3(B * 64 / 256), blk, 0, stream>>>(answer_hint, 512, 64, hint3, 512, 0);
    transpose_split3_w<<<dim3(8, 8), blk, 0, stream>>>(pool_Wq, 512, 512, poolWq3t);
    transpose_split3_w<<<dim3(8, 8), blk, 0, stream>>>(pool_Wm, 512, 512, poolWm3t);
    transpose_split3_w<<<dim3(16, 8), blk, 0, stream>>>(img_Wm, 1024, 512, imgWm3t);
    transpose_split3_w<<<dim3(16, 8), blk, 0, stream>>>(ppl_Wm, 1024, 512, pplWm3t);
    transpose_split3_w<<<dim3(16, 16), blk, 0, stream>>>(img_Wq, 1024, 1024, wq3t);
    transpose_split3_w<<<dim3(16, 16), blk, 0, stream>>>(ppl_Wq, 1024, 1024, wq3t + (size_t)1024 * 3072);

    // ---- precompute ----
    gemm3<64, 64, false, false><<<dim3(8, 2), blk, 0, stream>>>(hint3, poolWq3t, nullptr, nullptr, pool_qW, 512, 1536);
    gemm3<128, 128, false, true><<<dim3(4, 36), blk, 0, stream>>>(img3, poolWm3t, nullptr, pool_b, pool_mW, 512, 1536);
    attn_score<<<dim3(NI, B), blk, 0, stream>>>(pool_qW, 512, pool_mW, pool_v, pool_sc, NI, 512);
    attn_ctx_pool<<<dim3(B), blk, 0, stream>>>(pool_sc, img_feats, A2, NI);
    // g_pre = A2 @ visWih3^T + vis_b  (single fused GEMM, K3=3072)
    gemm3<128, 128, false, true><<<dim3(32, 20), blk, 0, stream>>>(A2, visWih3, nullptr, vis_bi, g_pre, G4, 3072);
    // attention memories -> f16 (+bias folded)
    gemm3<128, 128, false, true, 0, true><<<dim3(8, 36), blk, 0, stream>>>(img3, imgWm3t, nullptr, img_b, img_mW, H, 1536);
    gemm3<128, 128, false, true, 0, true><<<dim3(8, 100), blk, 0, stream>>>(ppl3, pplWm3t, nullptr, ppl_b, ppl_mW, H, 1536);

    // ---- sequential decode: combo[lang(t-1) || vis(t)] -> q_hh(t) -> attn(t) ----
    for (int t = 0; t <= T; ++t) {
        u16* x4_prev = x4 + (size_t)((t + 1) & 1) * B * 4608;   // x4(t-1): lang A input
        u16* x4_cur  = x4 + (size_t)(t & 1) * B * 4608;         // x4(t)
        u16* vis_A   = a3 + (size_t)(t & 1) * B * 3072;         // h_vis(t-1) triple
        u16* vis_o1  = a3 + (size_t)((t + 1) & 1) * B * 3072;   // h_vis(t) triple
        u16* hl_prev = hl3 + (size_t)((t + 1) & 1) * B * 3072;  // h_lang(t-1) triple
        u16* hl_out  = hl_prev;                                 // lang(t-1) writes h_lang(t-1)
        const float* gp = g_pre + (size_t)(t < T ? t : 0) * B * G4;
        step_combo<<<dim3(64, 2, 2), blk, 0, stream>>>(
            x4_prev, langWih3, gates_hh, c_lang, hl_out, h3_all,
            vis_A, visWhh3, gp, c_vis, vis_o1, x4_cur, t);
        if (t < T) {
            // q(t) from h_vis(t); lang-hh for step t: Whh @ h_lang(t-1) + bias
            gemm_q_hh<<<dim3(512), blk, 0, stream>>>(
                vis_o1, wq3t, qbuf, hl_prev, langWhh3, lang_bi, gates_hh);
            attn_fused<<<dim3(B), dim3(512), 0, stream>>>(qbuf, img_mW, ppl_mW, img_v, ppl_v,
                                                          img_feats, ppl_feats, x4_cur);
        }
    }

    // ---- deferred projection (super-tiled for L3 reuse) ----
    transpose_split3_w<<<dim3(313, 16), blk, 0, stream>>>(proj_W, V, 1024, projW3t);
    gemm3<128, 128, false, true, 20><<<dim3(157, 20), blk, 0, stream>>>(
        h3_all, projW3t, nullptr, proj_b, out, V, 3072);
    logsm_argmax<<<dim3(B * T), blk, 0, stream>>>(out);
}